// Round 1
// baseline (588.970 us; speedup 1.0000x reference)
//
#include <hip/hip_runtime.h>
#include <math.h>

#define NB 8
#define CIN 128
#define CDN 64
#define NPIX 16384            // 128*128
#define NHEADS 8
#define HDIM 8

struct alignas(8) c2 { float x, y; };

__device__ inline c2 cadd(c2 a, c2 b){ return {a.x+b.x, a.y+b.y}; }
__device__ inline c2 csub(c2 a, c2 b){ return {a.x-b.x, a.y-b.y}; }
__device__ inline c2 cmul(c2 a, c2 b){ return {a.x*b.x - a.y*b.y, a.x*b.y + a.y*b.x}; }
__device__ inline c2 shfl2(c2 v, int m){ return { __shfl_xor(v.x, m, 64), __shfl_xor(v.y, m, 64) }; }
__device__ inline float gelu_exact(float v){ return 0.5f*v*(1.f + erff(v*0.70710678118654752f)); }

// 128-pt FFT across one wave: lane t holds positions t (a) and t+64 (b).
// Forward: DIF, natural order in -> bit-reversed out.
__device__ inline void fft128_fwd(c2& a, c2& b, int t){
  float sn, cs;
  sincosf(-6.283185307179586f * (float)t * (1.f/128.f), &sn, &cs);
  c2 s = cadd(a,b), d = csub(a,b);
  a = s; b = cmul(d, c2{cs, sn});
  #pragma unroll
  for (int sp = 32; sp >= 1; sp >>= 1) {
    c2 oa = shfl2(a, sp), ob = shfl2(b, sp);
    int j = t & (sp-1);
    sincosf(-3.141592653589793f * (float)j / (float)sp, &sn, &cs);
    c2 w = {cs, sn};
    if (t & sp) { a = cmul(csub(oa,a), w); b = cmul(csub(ob,b), w); }
    else        { a = cadd(a,oa);          b = cadd(b,ob); }
  }
}

// Inverse (no 1/N scaling here): DIT, bit-reversed in -> natural out, conj twiddles.
__device__ inline void fft128_inv(c2& a, c2& b, int t){
  float sn, cs;
  #pragma unroll
  for (int sp = 1; sp <= 32; sp <<= 1) {
    c2 oa = shfl2(a, sp), ob = shfl2(b, sp);
    int j = t & (sp-1);
    sincosf(3.141592653589793f * (float)j / (float)sp, &sn, &cs);
    c2 w = {cs, sn};
    if (t & sp) { a = csub(oa, cmul(a, w)); b = csub(ob, cmul(b, w)); }
    else        { a = cadd(a, cmul(oa, w)); b = cadd(b, cmul(ob, w)); }
  }
  sincosf(6.283185307179586f * (float)t * (1.f/128.f), &sn, &cs);
  c2 wb = cmul(b, c2{cs, sn});
  b = csub(a, wb);
  a = cadd(a, wb);
}

// conv_w [64][128][3][3] -> wT [ci][tap][co]
__global__ __launch_bounds__(256) void k_wtrans(const float* __restrict__ w, float* __restrict__ wT){
  int i = blockIdx.x*256 + threadIdx.x;
  if (i < CDN*CIN*9) {
    int co = i / (CIN*9);
    int r  = i % (CIN*9);
    wT[r*CDN + co] = w[i];
  }
}

// Dilated 3x3 conv (dil=3, pad=3) + BN + exact GELU. 16x16 spatial tile, all 64 couts per block.
__global__ __launch_bounds__(256) void k_conv(const float* __restrict__ x, const float* __restrict__ wT,
    const float* __restrict__ bg, const float* __restrict__ bbeta,
    const float* __restrict__ bm, const float* __restrict__ bv,
    float* __restrict__ feat){
  __shared__ float sIn[22*24];
  __shared__ float sW[9*64];
  const int tid = threadIdx.x;
  const int bb = blockIdx.z;
  const int x0 = blockIdx.x * 16, y0 = blockIdx.y * 16;
  const int tx = tid & 3;          // 4 x-blocks of 4 cols
  const int tc = (tid >> 2) & 7;   // 8 co-blocks of 8
  const int ty = tid >> 5;         // 8 y-blocks of 2 rows
  float acc[2][4][8];
  #pragma unroll
  for (int iy=0;iy<2;++iy)
    #pragma unroll
    for (int ix=0;ix<4;++ix)
      #pragma unroll
      for (int c=0;c<8;++c) acc[iy][ix][c] = 0.f;
  const float* xb = x + (size_t)bb*CIN*NPIX;
  for (int ci = 0; ci < CIN; ++ci) {
    __syncthreads();
    for (int i = tid; i < 22*22; i += 256) {
      int iy = i / 22, ix = i - iy*22;
      int gy = y0 - 3 + iy, gx = x0 - 3 + ix;
      float v = 0.f;
      if ((unsigned)gy < 128u && (unsigned)gx < 128u) v = xb[ci*NPIX + gy*128 + gx];
      sIn[iy*24 + ix] = v;
    }
    for (int i = tid; i < 576; i += 256) sW[i] = wT[ci*576 + i];
    __syncthreads();
    #pragma unroll
    for (int ky = 0; ky < 3; ++ky)
    #pragma unroll
    for (int kx = 0; kx < 3; ++kx) {
      float wv[8];
      #pragma unroll
      for (int c = 0; c < 8; ++c) wv[c] = sW[(ky*3+kx)*64 + tc*8 + c];
      #pragma unroll
      for (int iy = 0; iy < 2; ++iy) {
        const float* ip = &sIn[(ty*2+iy + ky*3)*24 + tx*4 + kx*3];
        float iv[4];
        #pragma unroll
        for (int ix = 0; ix < 4; ++ix) iv[ix] = ip[ix];
        #pragma unroll
        for (int ix = 0; ix < 4; ++ix)
          #pragma unroll
          for (int c = 0; c < 8; ++c)
            acc[iy][ix][c] += iv[ix] * wv[c];
      }
    }
  }
  #pragma unroll
  for (int c = 0; c < 8; ++c) {
    int co = tc*8 + c;
    float sc = bg[co] * rsqrtf(bv[co] + 1e-5f);
    float sh = bbeta[co] - bm[co]*sc;
    #pragma unroll
    for (int iy = 0; iy < 2; ++iy) {
      int yy = y0 + ty*2 + iy;
      #pragma unroll
      for (int ix = 0; ix < 4; ++ix) {
        float v = acc[iy][ix][c]*sc + sh;
        feat[((size_t)(bb*CDN + co)*128 + yy)*128 + x0 + tx*4 + ix] = gelu_exact(v);
      }
    }
  }
}

// Per (b,h): 8x8 spatial Gram -> complex-free attention (Plancherel), softmax rows.
__global__ __launch_bounds__(256) void k_attn(const float* __restrict__ feat, const float* __restrict__ tau,
                                              float* __restrict__ attn){
  int bh = blockIdx.x; int b = bh >> 3, h = bh & 7;
  const float* f = feat + (size_t)(b*CDN + h*HDIM)*NPIX;
  float acc[36];
  #pragma unroll
  for (int i=0;i<36;++i) acc[i]=0.f;
  for (int p = threadIdx.x; p < NPIX; p += 256) {
    float v[8];
    #pragma unroll
    for (int d=0; d<8; ++d) v[d] = f[d*NPIX + p];
    int i = 0;
    #pragma unroll
    for (int d=0; d<8; ++d)
      #pragma unroll
      for (int e=0; e<=d; ++e) acc[i++] += v[d]*v[e];
  }
  #pragma unroll
  for (int i=0;i<36;++i)
    #pragma unroll
    for (int off=32; off; off>>=1) acc[i] += __shfl_xor(acc[i], off, 64);
  __shared__ float red[4][36];
  int wave = threadIdx.x >> 6, lane = threadIdx.x & 63;
  if (lane == 0) {
    #pragma unroll
    for (int i=0;i<36;++i) red[wave][i] = acc[i];
  }
  __syncthreads();
  if (threadIdx.x == 0) {
    float G[8][8];
    int i=0;
    for (int d=0;d<8;++d) for(int e=0;e<=d;++e){
      float s = red[0][i]+red[1][i]+red[2][i]+red[3][i];
      G[d][e]=s; G[e][d]=s; ++i;
    }
    float nrm[8];
    for (int d=0;d<8;++d) nrm[d] = sqrtf(16384.f*G[d][d] + 1e-6f);
    float tv = tau[h];
    for (int d=0;d<8;++d) {
      float row[8]; float mx = -1e30f;
      for (int e=0;e<8;++e){ row[e] = tv*16384.f*G[d][e]/(nrm[d]*nrm[e]); mx = fmaxf(mx,row[e]); }
      float s=0.f;
      for (int e=0;e<8;++e){ row[e] = expf(row[e]-mx); s += row[e]; }
      for (int e=0;e<8;++e) attn[bh*64 + d*8 + e] = row[e]/s;
    }
  }
}

// out_f = sqrt((attn_re @ feat)^2 + (mean_e feat)^2) + x   (channels 0..63)
__global__ __launch_bounds__(256) void k_outf(const float* __restrict__ feat, const float* __restrict__ attn,
                                              const float* __restrict__ x, float* __restrict__ out){
  int bh = blockIdx.x; int b = bh >> 3, h = bh & 7;
  int p = blockIdx.y*256 + threadIdx.x;
  __shared__ float A[64];
  if (threadIdx.x < 64) A[threadIdx.x] = attn[bh*64 + threadIdx.x];
  __syncthreads();
  const float* f = feat + (size_t)(b*CDN + h*HDIM)*NPIX;
  float v[8];
  #pragma unroll
  for (int e=0;e<8;++e) v[e] = f[e*NPIX + p];
  float im = 0.f;
  #pragma unroll
  for (int e=0;e<8;++e) im += v[e];
  im *= 0.125f;
  #pragma unroll
  for (int d=0;d<8;++d){
    float re = 0.f;
    #pragma unroll
    for (int e=0;e<8;++e) re += A[d*8+e]*v[e];
    size_t o = ((size_t)(b*CIN + h*HDIM + d))*NPIX + p;
    out[o] = sqrtf(re*re + im*im) + x[o];
  }
}

// forward row FFT: feat (real) -> FC (complex, W-axis bit-rev)
__global__ __launch_bounds__(256) void k_fft_rows(const float* __restrict__ feat, c2* __restrict__ FC){
  int ib = blockIdx.x;
  int wave = threadIdx.x >> 6, t = threadIdx.x & 63;
  const float* src = feat + (size_t)ib*NPIX;
  c2* dst = FC + (size_t)ib*NPIX;
  for (int r = wave; r < 128; r += 4) {
    c2 a = {src[r*128 + t], 0.f};
    c2 b = {src[r*128 + t + 64], 0.f};
    fft128_fwd(a, b, t);
    dst[r*128 + t] = a;
    dst[r*128 + t + 64] = b;
  }
}

// forward column FFT, in place
__global__ __launch_bounds__(256) void k_fft_cols(c2* __restrict__ FC){
  int ib = blockIdx.x;
  int wave = threadIdx.x >> 6, t = threadIdx.x & 63;
  c2* img = FC + (size_t)ib*NPIX;
  for (int c = wave; c < 128; c += 4) {
    c2 a = img[t*128 + c];
    c2 b = img[(t+64)*128 + c];
    fft128_fwd(a, b, t);
    img[t*128 + c] = a;
    img[(t+64)*128 + c] = b;
  }
}

// gate MLP per frequency bin: cg = sigmoid(W2 gelu(bn(W1 Re(F)+b1)) + b2); F *= cg. In place.
__global__ __launch_bounds__(256) void k_gate(c2* __restrict__ FC,
    const float* __restrict__ w1, const float* __restrict__ b1,
    const float* __restrict__ gg, const float* __restrict__ gbeta,
    const float* __restrict__ gm, const float* __restrict__ gv,
    const float* __restrict__ w2, const float* __restrict__ b2){
  int b = blockIdx.x >> 6;
  int p = (blockIdx.x & 63)*256 + threadIdx.x;
  c2* base = FC + (size_t)b*CDN*NPIX;
  c2 v[64];
  float mid[4];
  #pragma unroll
  for (int m=0;m<4;++m) mid[m] = b1[m];
  #pragma unroll
  for (int c=0;c<64;++c) {
    v[c] = base[(size_t)c*NPIX + p];
    #pragma unroll
    for (int m=0;m<4;++m) mid[m] += w1[m*64+c]*v[c].x;
  }
  #pragma unroll
  for (int m=0;m<4;++m) {
    float sc = gg[m]*rsqrtf(gv[m]+1e-5f);
    float sh = gbeta[m] - gm[m]*sc;
    mid[m] = gelu_exact(mid[m]*sc + sh);
  }
  #pragma unroll
  for (int c=0;c<64;++c) {
    float s = b2[c];
    #pragma unroll
    for (int m=0;m<4;++m) s += w2[c*4+m]*mid[m];
    s = 1.f/(1.f+expf(-s));
    v[c].x *= s; v[c].y *= s;
    base[(size_t)c*NPIX + p] = v[c];
  }
}

// inverse column FFT, in place, scaled by 1/128
__global__ __launch_bounds__(256) void k_ifft_cols(c2* __restrict__ FC){
  int ib = blockIdx.x;
  int wave = threadIdx.x >> 6, t = threadIdx.x & 63;
  c2* img = FC + (size_t)ib*NPIX;
  const float s = 1.f/128.f;
  for (int c = wave; c < 128; c += 4) {
    c2 a = img[t*128 + c];
    c2 b = img[(t+64)*128 + c];
    fft128_inv(a, b, t);
    a.x*=s; a.y*=s; b.x*=s; b.y*=s;
    img[t*128 + c] = a;
    img[(t+64)*128 + c] = b;
  }
}

// inverse row FFT + abs + residual -> out channels 64..127
__global__ __launch_bounds__(256) void k_ifft_rows_out(const c2* __restrict__ FC, const float* __restrict__ x,
                                                       float* __restrict__ out){
  int ib = blockIdx.x;                 // b*64 + c
  int b = ib >> 6, c = ib & 63;
  int wave = threadIdx.x >> 6, t = threadIdx.x & 63;
  const c2* src = FC + (size_t)ib*NPIX;
  const float s = 1.f/128.f;
  for (int r = wave; r < 128; r += 4) {
    c2 a = src[r*128 + t];
    c2 bb = src[r*128 + t + 64];
    fft128_inv(a, bb, t);
    float m0 = sqrtf(a.x*a.x + a.y*a.y)*s;
    float m1 = sqrtf(bb.x*bb.x + bb.y*bb.y)*s;
    size_t o = ((size_t)(b*CIN + 64 + c))*NPIX + (size_t)r*128;
    out[o + t]      = m0 + x[o + t];
    out[o + t + 64] = m1 + x[o + t + 64];
  }
}

extern "C" void kernel_launch(void* const* d_in, const int* in_sizes, int n_in,
                              void* d_out, int out_size, void* d_ws, size_t ws_size,
                              hipStream_t stream){
  const float* x      = (const float*)d_in[0];
  const float* conv_w = (const float*)d_in[1];
  const float* bn1_g  = (const float*)d_in[2];
  const float* bn1_b  = (const float*)d_in[3];
  const float* bn1_m  = (const float*)d_in[4];
  const float* bn1_v  = (const float*)d_in[5];
  const float* cg1_w  = (const float*)d_in[6];
  const float* cg1_b  = (const float*)d_in[7];
  const float* cgbn_g = (const float*)d_in[8];
  const float* cgbn_b = (const float*)d_in[9];
  const float* cgbn_m = (const float*)d_in[10];
  const float* cgbn_v = (const float*)d_in[11];
  const float* cg2_w  = (const float*)d_in[12];
  const float* cg2_b  = (const float*)d_in[13];
  const float* tau    = (const float*)d_in[14];
  float* out = (float*)d_out;

  char* ws = (char*)d_ws;
  float* feat = (float*)ws;                          // 33,554,432 B
  c2*    FC   = (c2*)(ws + 33554432);                // 67,108,864 B
  float* wT   = (float*)(ws + 33554432 + 67108864);  //    294,912 B
  float* attn = (float*)(ws + 33554432 + 67108864 + 294912); // 16,384 B

  k_wtrans<<<288, 256, 0, stream>>>(conv_w, wT);
  k_conv<<<dim3(8,8,NB), 256, 0, stream>>>(x, wT, bn1_g, bn1_b, bn1_m, bn1_v, feat);
  k_attn<<<NB*NHEADS, 256, 0, stream>>>(feat, tau, attn);
  k_outf<<<dim3(NB*NHEADS, 64), 256, 0, stream>>>(feat, attn, x, out);
  k_fft_rows<<<NB*CDN, 256, 0, stream>>>(feat, FC);
  k_fft_cols<<<NB*CDN, 256, 0, stream>>>(FC);
  k_gate<<<NB*64, 256, 0, stream>>>(FC, cg1_w, cg1_b, cgbn_g, cgbn_b, cgbn_m, cgbn_v, cg2_w, cg2_b);
  k_ifft_cols<<<NB*CDN, 256, 0, stream>>>(FC);
  k_ifft_rows_out<<<NB*CDN, 256, 0, stream>>>(FC, x, out);
}

// Round 2
// 421.461 us; speedup vs baseline: 1.3974x; 1.3974x over previous
//
#include <hip/hip_runtime.h>
#include <hip/hip_bf16.h>
#include <math.h>

#define NB 8
#define CIN 128
#define CDN 64
#define NPIX 16384            // 128*128
#define NHEADS 8
#define HDIM 8

typedef __attribute__((ext_vector_type(8))) short bf16x8;
typedef __attribute__((ext_vector_type(4))) float f32x4;

struct alignas(8) c2 { float x, y; };

__device__ inline c2 cadd(c2 a, c2 b){ return {a.x+b.x, a.y+b.y}; }
__device__ inline c2 csub(c2 a, c2 b){ return {a.x-b.x, a.y-b.y}; }
__device__ inline c2 cmul(c2 a, c2 b){ return {a.x*b.x - a.y*b.y, a.x*b.y + a.y*b.x}; }
__device__ inline c2 shfl2(c2 v, int m){ return { __shfl_xor(v.x, m, 64), __shfl_xor(v.y, m, 64) }; }
__device__ inline float gelu_exact(float v){ return 0.5f*v*(1.f + erff(v*0.70710678118654752f)); }
__device__ inline unsigned short f2bf(float f){
  __hip_bfloat16 h = __float2bfloat16(f);
  return *reinterpret_cast<unsigned short*>(&h);
}

// 128-pt FFT across one wave: lane t holds positions t (a) and t+64 (b).
// Forward: DIF, natural order in -> bit-reversed out.
__device__ inline void fft128_fwd(c2& a, c2& b, int t){
  float sn, cs;
  sincosf(-6.283185307179586f * (float)t * (1.f/128.f), &sn, &cs);
  c2 s = cadd(a,b), d = csub(a,b);
  a = s; b = cmul(d, c2{cs, sn});
  #pragma unroll
  for (int sp = 32; sp >= 1; sp >>= 1) {
    c2 oa = shfl2(a, sp), ob = shfl2(b, sp);
    int j = t & (sp-1);
    sincosf(-3.141592653589793f * (float)j / (float)sp, &sn, &cs);
    c2 w = {cs, sn};
    if (t & sp) { a = cmul(csub(oa,a), w); b = cmul(csub(ob,b), w); }
    else        { a = cadd(a,oa);          b = cadd(b,ob); }
  }
}

// Inverse (no 1/N scaling here): DIT, bit-reversed in -> natural out, conj twiddles.
__device__ inline void fft128_inv(c2& a, c2& b, int t){
  float sn, cs;
  #pragma unroll
  for (int sp = 1; sp <= 32; sp <<= 1) {
    c2 oa = shfl2(a, sp), ob = shfl2(b, sp);
    int j = t & (sp-1);
    sincosf(3.141592653589793f * (float)j / (float)sp, &sn, &cs);
    c2 w = {cs, sn};
    if (t & sp) { a = csub(oa, cmul(a, w)); b = csub(ob, cmul(b, w)); }
    else        { a = cadd(a, cmul(oa, w)); b = cadd(b, cmul(ob, w)); }
  }
  sincosf(6.283185307179586f * (float)t * (1.f/128.f), &sn, &cs);
  c2 wb = cmul(b, c2{cs, sn});
  b = csub(a, wb);
  a = cadd(a, wb);
}

// conv_w fp32 [64co][128ci][3][3] -> wPack bf16 [cc=2][tap=9][co=64][ci=64] (plain, K-contiguous)
__global__ __launch_bounds__(256) void k_wpack(const float* __restrict__ w, unsigned short* __restrict__ wP){
  int idx = blockIdx.x*256 + threadIdx.x;
  if (idx >= 2*9*64*64) return;
  int cc  = idx / 36864;
  int r   = idx - cc*36864;
  int tap = r / 4096;
  int r2  = r - tap*4096;
  int co  = r2 >> 6;
  int cil = r2 & 63;
  int ci  = cc*64 + cil;
  wP[idx] = f2bf(w[(co*CIN + ci)*9 + tap]);
}

// Dilated 3x3 conv (dil=3,pad=3) + BN + exact GELU via bf16 MFMA implicit GEMM.
// Block: 16x16 output tile, all 64 couts. M=co(64), N=pixels(256), K=2cc*9tap*64ci.
__global__ __launch_bounds__(256) void k_conv(const float* __restrict__ x, const unsigned short* __restrict__ wP,
    const float* __restrict__ bg, const float* __restrict__ bbeta,
    const float* __restrict__ bm, const float* __restrict__ bv,
    float* __restrict__ feat){
  __shared__ unsigned short sX[484*64];   // [haloPixel 22x22][ci 64] bf16, 16B-granule XOR swizzle by (p&7)
  const int tid = threadIdx.x;
  const int bb = blockIdx.z;
  const int x0 = blockIdx.x * 16, y0 = blockIdx.y * 16;
  const int wv  = tid >> 6;
  const int l   = tid & 63;
  const int l15 = l & 15;
  const int g   = l >> 4;            // k-group 0..3

  f32x4 acc[4][4];
  #pragma unroll
  for (int m=0;m<4;++m)
    #pragma unroll
    for (int n=0;n<4;++n) acc[m][n] = {0.f,0.f,0.f,0.f};

  const float* xb = x + (size_t)bb*CIN*NPIX;

  // precompute the two staging pixels this thread owns
  int p0 = tid, p1 = tid + 256;      // p1 < 484 check below
  int py0 = p0 / 22, px0 = p0 - py0*22;
  int py1 = p1 / 22, px1 = p1 - py1*22;
  int gy0 = y0 - 3 + py0, gx0 = x0 - 3 + px0;
  int gy1 = y0 - 3 + py1, gx1 = x0 - 3 + px1;
  bool ok0 = ((unsigned)gy0 < 128u) && ((unsigned)gx0 < 128u);
  bool ok1 = (p1 < 484) && ((unsigned)gy1 < 128u) && ((unsigned)gx1 < 128u);
  int go0 = gy0*128 + gx0, go1 = gy1*128 + gx1;
  int lb0 = p0*64, sw0 = (p0 & 7) << 3;
  int lb1 = p1*64, sw1 = (p1 & 7) << 3;

  for (int cc = 0; cc < 2; ++cc) {
    __syncthreads();
    // stage halo chunk: 484 px x 64 ci, bf16, swizzled
    const float* srcc = xb + (size_t)(cc*64)*NPIX;
    #pragma unroll 8
    for (int ci = 0; ci < 64; ++ci) {
      float v0 = ok0 ? srcc[(size_t)ci*NPIX + go0] : 0.f;
      sX[lb0 + (ci ^ sw0)] = f2bf(v0);
      if (p1 < 484) {
        float v1 = ok1 ? srcc[(size_t)ci*NPIX + go1] : 0.f;
        sX[lb1 + (ci ^ sw1)] = f2bf(v1);
      }
    }
    __syncthreads();

    const unsigned short* wcc = wP + cc*36864;
    for (int tap = 0; tap < 9; ++tap) {
      int dy = (tap/3)*3, dx = (tap - (tap/3)*3)*3;
      const unsigned short* wt = wcc + tap*4096;
      #pragma unroll
      for (int kc = 0; kc < 2; ++kc) {
        bf16x8 a[4], b[4];
        int ko = kc*32 + g*8;
        #pragma unroll
        for (int m = 0; m < 4; ++m)
          a[m] = *reinterpret_cast<const bf16x8*>(wt + (m*16 + l15)*64 + ko);
        #pragma unroll
        for (int n = 0; n < 4; ++n) {
          int p = (wv*4 + n + dy)*22 + l15 + dx;
          b[n] = *reinterpret_cast<const bf16x8*>(&sX[p*64 + (ko ^ ((p & 7) << 3))]);
        }
        #pragma unroll
        for (int m = 0; m < 4; ++m)
          #pragma unroll
          for (int n = 0; n < 4; ++n)
            acc[m][n] = __builtin_amdgcn_mfma_f32_16x16x32_bf16(a[m], b[n], acc[m][n], 0, 0, 0);
      }
    }
  }

  // epilogue: BN + GELU, store fp32 feat. D: col(l15)=pixel-x, row=g*4+r within m-frag (=co)
  #pragma unroll
  for (int m = 0; m < 4; ++m) {
    #pragma unroll
    for (int r = 0; r < 4; ++r) {
      int co = m*16 + g*4 + r;
      float sc = bg[co] * rsqrtf(bv[co] + 1e-5f);
      float sh = bbeta[co] - bm[co]*sc;
      #pragma unroll
      for (int n = 0; n < 4; ++n) {
        int py = wv*4 + n;
        float v = acc[m][n][r]*sc + sh;
        feat[((size_t)(bb*CDN + co)*128 + (y0+py))*128 + x0 + l15] = gelu_exact(v);
      }
    }
  }
}

// Per (b,h): 8x8 spatial Gram -> complex-free attention (Plancherel), softmax rows.
__global__ __launch_bounds__(256) void k_attn(const float* __restrict__ feat, const float* __restrict__ tau,
                                              float* __restrict__ attn){
  int bh = blockIdx.x; int b = bh >> 3, h = bh & 7;
  const float* f = feat + (size_t)(b*CDN + h*HDIM)*NPIX;
  float acc[36];
  #pragma unroll
  for (int i=0;i<36;++i) acc[i]=0.f;
  for (int p = threadIdx.x; p < NPIX; p += 256) {
    float v[8];
    #pragma unroll
    for (int d=0; d<8; ++d) v[d] = f[d*NPIX + p];
    int i = 0;
    #pragma unroll
    for (int d=0; d<8; ++d)
      #pragma unroll
      for (int e=0; e<=d; ++e) acc[i++] += v[d]*v[e];
  }
  #pragma unroll
  for (int i=0;i<36;++i)
    #pragma unroll
    for (int off=32; off; off>>=1) acc[i] += __shfl_xor(acc[i], off, 64);
  __shared__ float red[4][36];
  int wave = threadIdx.x >> 6, lane = threadIdx.x & 63;
  if (lane == 0) {
    #pragma unroll
    for (int i=0;i<36;++i) red[wave][i] = acc[i];
  }
  __syncthreads();
  if (threadIdx.x == 0) {
    float G[8][8];
    int i=0;
    for (int d=0;d<8;++d) for(int e=0;e<=d;++e){
      float s = red[0][i]+red[1][i]+red[2][i]+red[3][i];
      G[d][e]=s; G[e][d]=s; ++i;
    }
    float nrm[8];
    for (int d=0;d<8;++d) nrm[d] = sqrtf(16384.f*G[d][d] + 1e-6f);
    float tv = tau[h];
    for (int d=0;d<8;++d) {
      float row[8]; float mx = -1e30f;
      for (int e=0;e<8;++e){ row[e] = tv*16384.f*G[d][e]/(nrm[d]*nrm[e]); mx = fmaxf(mx,row[e]); }
      float s=0.f;
      for (int e=0;e<8;++e){ row[e] = expf(row[e]-mx); s += row[e]; }
      for (int e=0;e<8;++e) attn[bh*64 + d*8 + e] = row[e]/s;
    }
  }
}

// out_f = sqrt((attn_re @ feat)^2 + (mean_e feat)^2) + x   (channels 0..63)
__global__ __launch_bounds__(256) void k_outf(const float* __restrict__ feat, const float* __restrict__ attn,
                                              const float* __restrict__ x, float* __restrict__ out){
  int bh = blockIdx.x; int b = bh >> 3, h = bh & 7;
  int p = blockIdx.y*256 + threadIdx.x;
  __shared__ float A[64];
  if (threadIdx.x < 64) A[threadIdx.x] = attn[bh*64 + threadIdx.x];
  __syncthreads();
  const float* f = feat + (size_t)(b*CDN + h*HDIM)*NPIX;
  float v[8];
  #pragma unroll
  for (int e=0;e<8;++e) v[e] = f[e*NPIX + p];
  float im = 0.f;
  #pragma unroll
  for (int e=0;e<8;++e) im += v[e];
  im *= 0.125f;
  #pragma unroll
  for (int d=0;d<8;++d){
    float re = 0.f;
    #pragma unroll
    for (int e=0;e<8;++e) re += A[d*8+e]*v[e];
    size_t o = ((size_t)(b*CIN + h*HDIM + d))*NPIX + p;
    out[o] = sqrtf(re*re + im*im) + x[o];
  }
}

// forward row FFT: feat (real) -> FC (complex, W-axis bit-rev)
__global__ __launch_bounds__(256) void k_fft_rows(const float* __restrict__ feat, c2* __restrict__ FC){
  int ib = blockIdx.x;
  int wave = threadIdx.x >> 6, t = threadIdx.x & 63;
  const float* src = feat + (size_t)ib*NPIX;
  c2* dst = FC + (size_t)ib*NPIX;
  for (int r = wave; r < 128; r += 4) {
    c2 a = {src[r*128 + t], 0.f};
    c2 b = {src[r*128 + t + 64], 0.f};
    fft128_fwd(a, b, t);
    dst[r*128 + t] = a;
    dst[r*128 + t + 64] = b;
  }
}

// forward column FFT, in place
__global__ __launch_bounds__(256) void k_fft_cols(c2* __restrict__ FC){
  int ib = blockIdx.x;
  int wave = threadIdx.x >> 6, t = threadIdx.x & 63;
  c2* img = FC + (size_t)ib*NPIX;
  for (int c = wave; c < 128; c += 4) {
    c2 a = img[t*128 + c];
    c2 b = img[(t+64)*128 + c];
    fft128_fwd(a, b, t);
    img[t*128 + c] = a;
    img[(t+64)*128 + c] = b;
  }
}

// gate MLP per frequency bin: cg = sigmoid(W2 gelu(bn(W1 Re(F)+b1)) + b2); F *= cg. In place.
__global__ __launch_bounds__(256) void k_gate(c2* __restrict__ FC,
    const float* __restrict__ w1, const float* __restrict__ b1,
    const float* __restrict__ gg, const float* __restrict__ gbeta,
    const float* __restrict__ gm, const float* __restrict__ gv,
    const float* __restrict__ w2, const float* __restrict__ b2){
  int b = blockIdx.x >> 6;
  int p = (blockIdx.x & 63)*256 + threadIdx.x;
  c2* base = FC + (size_t)b*CDN*NPIX;
  c2 v[64];
  float mid[4];
  #pragma unroll
  for (int m=0;m<4;++m) mid[m] = b1[m];
  #pragma unroll
  for (int c=0;c<64;++c) {
    v[c] = base[(size_t)c*NPIX + p];
    #pragma unroll
    for (int m=0;m<4;++m) mid[m] += w1[m*64+c]*v[c].x;
  }
  #pragma unroll
  for (int m=0;m<4;++m) {
    float sc = gg[m]*rsqrtf(gv[m]+1e-5f);
    float sh = gbeta[m] - gm[m]*sc;
    mid[m] = gelu_exact(mid[m]*sc + sh);
  }
  #pragma unroll
  for (int c=0;c<64;++c) {
    float s = b2[c];
    #pragma unroll
    for (int m=0;m<4;++m) s += w2[c*4+m]*mid[m];
    s = 1.f/(1.f+expf(-s));
    v[c].x *= s; v[c].y *= s;
    base[(size_t)c*NPIX + p] = v[c];
  }
}

// inverse column FFT, in place, scaled by 1/128
__global__ __launch_bounds__(256) void k_ifft_cols(c2* __restrict__ FC){
  int ib = blockIdx.x;
  int wave = threadIdx.x >> 6, t = threadIdx.x & 63;
  c2* img = FC + (size_t)ib*NPIX;
  const float s = 1.f/128.f;
  for (int c = wave; c < 128; c += 4) {
    c2 a = img[t*128 + c];
    c2 b = img[(t+64)*128 + c];
    fft128_inv(a, b, t);
    a.x*=s; a.y*=s; b.x*=s; b.y*=s;
    img[t*128 + c] = a;
    img[(t+64)*128 + c] = b;
  }
}

// inverse row FFT + abs + residual -> out channels 64..127
__global__ __launch_bounds__(256) void k_ifft_rows_out(const c2* __restrict__ FC, const float* __restrict__ x,
                                                       float* __restrict__ out){
  int ib = blockIdx.x;                 // b*64 + c
  int b = ib >> 6, c = ib & 63;
  int wave = threadIdx.x >> 6, t = threadIdx.x & 63;
  const c2* src = FC + (size_t)ib*NPIX;
  const float s = 1.f/128.f;
  for (int r = wave; r < 128; r += 4) {
    c2 a = src[r*128 + t];
    c2 bb = src[r*128 + t + 64];
    fft128_inv(a, bb, t);
    float m0 = sqrtf(a.x*a.x + a.y*a.y)*s;
    float m1 = sqrtf(bb.x*bb.x + bb.y*bb.y)*s;
    size_t o = ((size_t)(b*CIN + 64 + c))*NPIX + (size_t)r*128;
    out[o + t]      = m0 + x[o + t];
    out[o + t + 64] = m1 + x[o + t + 64];
  }
}

extern "C" void kernel_launch(void* const* d_in, const int* in_sizes, int n_in,
                              void* d_out, int out_size, void* d_ws, size_t ws_size,
                              hipStream_t stream){
  const float* x      = (const float*)d_in[0];
  const float* conv_w = (const float*)d_in[1];
  const float* bn1_g  = (const float*)d_in[2];
  const float* bn1_b  = (const float*)d_in[3];
  const float* bn1_m  = (const float*)d_in[4];
  const float* bn1_v  = (const float*)d_in[5];
  const float* cg1_w  = (const float*)d_in[6];
  const float* cg1_b  = (const float*)d_in[7];
  const float* cgbn_g = (const float*)d_in[8];
  const float* cgbn_b = (const float*)d_in[9];
  const float* cgbn_m = (const float*)d_in[10];
  const float* cgbn_v = (const float*)d_in[11];
  const float* cg2_w  = (const float*)d_in[12];
  const float* cg2_b  = (const float*)d_in[13];
  const float* tau    = (const float*)d_in[14];
  float* out = (float*)d_out;

  char* ws = (char*)d_ws;
  float*          feat  = (float*)ws;                          // 33,554,432 B
  c2*             FC    = (c2*)(ws + 33554432);                // 67,108,864 B
  unsigned short* wPack = (unsigned short*)(ws + 33554432 + 67108864); // 147,456 B
  float*          attn  = (float*)(ws + 33554432 + 67108864 + 147456); // 16,384 B

  k_wpack<<<288, 256, 0, stream>>>(conv_w, wPack);
  k_conv<<<dim3(8,8,NB), 256, 0, stream>>>(x, wPack, bn1_g, bn1_b, bn1_m, bn1_v, feat);
  k_attn<<<NB*NHEADS, 256, 0, stream>>>(feat, tau, attn);
  k_outf<<<dim3(NB*NHEADS, 64), 256, 0, stream>>>(feat, attn, x, out);
  k_fft_rows<<<NB*CDN, 256, 0, stream>>>(feat, FC);
  k_fft_cols<<<NB*CDN, 256, 0, stream>>>(FC);
  k_gate<<<NB*64, 256, 0, stream>>>(FC, cg1_w, cg1_b, cgbn_g, cgbn_b, cgbn_m, cgbn_v, cg2_w, cg2_b);
  k_ifft_cols<<<NB*CDN, 256, 0, stream>>>(FC);
  k_ifft_rows_out<<<NB*CDN, 256, 0, stream>>>(FC, x, out);
}

// Round 3
// 355.336 us; speedup vs baseline: 1.6575x; 1.1861x over previous
//
#include <hip/hip_runtime.h>
#include <hip/hip_bf16.h>
#include <math.h>

#define NB 8
#define CIN 128
#define CDN 64
#define NPIX 16384            // 128*128
#define NHEADS 8
#define HDIM 8

typedef __attribute__((ext_vector_type(8))) short bf16x8;
typedef __attribute__((ext_vector_type(4))) float f32x4;
typedef __attribute__((ext_vector_type(8))) unsigned short u16x8;
typedef __attribute__((ext_vector_type(4))) unsigned short u16x4;

struct alignas(8) c2 { float x, y; };

__device__ inline c2 cadd(c2 a, c2 b){ return {a.x+b.x, a.y+b.y}; }
__device__ inline c2 csub(c2 a, c2 b){ return {a.x-b.x, a.y-b.y}; }
__device__ inline c2 cmul(c2 a, c2 b){ return {a.x*b.x - a.y*b.y, a.x*b.y + a.y*b.x}; }
__device__ inline c2 shfl2(c2 v, int m){ return { __shfl_xor(v.x, m, 64), __shfl_xor(v.y, m, 64) }; }
__device__ inline float gelu_exact(float v){ return 0.5f*v*(1.f + erff(v*0.70710678118654752f)); }
__device__ inline unsigned short f2bf(float f){
  __hip_bfloat16 h = __float2bfloat16(f);
  return *reinterpret_cast<unsigned short*>(&h);
}

// ---- twiddle-hoisted 128-pt wave FFT: lane t holds positions t and t+64 ----
struct Tw { c2 t0; c2 t[6]; };
__device__ inline void tw_init(Tw& w, int t){
  float sn, cs;
  sincosf(-6.283185307179586f * (float)t * (1.f/128.f), &sn, &cs); w.t0 = {cs, sn};
  #pragma unroll
  for (int i = 0; i < 6; ++i) {
    int sp = 32 >> i;
    int j = t & (sp-1);
    sincosf(-3.141592653589793f * (float)j / (float)sp, &sn, &cs);
    w.t[i] = {cs, sn};
  }
}
// forward DIF: natural in -> slot order out
__device__ inline void fft128_fwd(c2& a, c2& b, int t, const Tw& w){
  c2 s = cadd(a,b), d = csub(a,b);
  a = s; b = cmul(d, w.t0);
  #pragma unroll
  for (int i = 0; i < 6; ++i) {
    int sp = 32 >> i;
    c2 oa = shfl2(a, sp), ob = shfl2(b, sp);
    c2 tw = w.t[i];
    if (t & sp) { a = cmul(csub(oa,a), tw); b = cmul(csub(ob,b), tw); }
    else        { a = cadd(a,oa);           b = cadd(b,ob); }
  }
}
// inverse DIT (no scaling): slot order in -> natural out
__device__ inline void fft128_inv(c2& a, c2& b, int t, const Tw& w){
  #pragma unroll
  for (int i = 5; i >= 0; --i) {
    int sp = 32 >> i;
    c2 tw = {w.t[i].x, -w.t[i].y};
    c2 oa = shfl2(a, sp), ob = shfl2(b, sp);
    if (t & sp) { a = csub(oa, cmul(a, tw)); b = csub(ob, cmul(b, tw)); }
    else        { a = cadd(a, cmul(oa, tw)); b = cadd(b, cmul(ob, tw)); }
  }
  c2 t0c = {w.t0.x, -w.t0.y};
  c2 wb = cmul(b, t0c);
  b = csub(a, wb);
  a = cadd(a, wb);
}

__device__ inline void gload_lds16(const void* g, void* l){
  __builtin_amdgcn_global_load_lds(
      (const __attribute__((address_space(1))) unsigned int*)g,
      (__attribute__((address_space(3))) unsigned int*)l, 16, 0, 0);
}

// conv_w fp32 [64co][128ci][3][3] -> wPack bf16 [cc=2][tap=9][co=64][ci=64]
__global__ __launch_bounds__(256) void k_wpack(const float* __restrict__ w, unsigned short* __restrict__ wP){
  int idx = blockIdx.x*256 + threadIdx.x;
  if (idx >= 2*9*64*64) return;
  int cc  = idx / 36864;
  int r   = idx - cc*36864;
  int tap = r / 4096;
  int r2  = r - tap*4096;
  int co  = r2 >> 6;
  int cil = r2 & 63;
  int ci  = cc*64 + cil;
  wP[idx] = f2bf(w[(co*CIN + ci)*9 + tap]);
}

// x fp32 [b][128ci][16384p] -> xT bf16 [b][2cc][16384p][64ci]
__global__ __launch_bounds__(256) void k_xpose(const float* __restrict__ x, unsigned short* __restrict__ xT){
  int b = blockIdx.x >> 6;
  int px = (blockIdx.x & 63)*256 + threadIdx.x;
  const float* xb = x + (size_t)b*CIN*NPIX + px;
  #pragma unroll 4
  for (int ci0 = 0; ci0 < 128; ci0 += 4) {
    u16x4 v;
    v[0] = f2bf(xb[(size_t)(ci0+0)*NPIX]);
    v[1] = f2bf(xb[(size_t)(ci0+1)*NPIX]);
    v[2] = f2bf(xb[(size_t)(ci0+2)*NPIX]);
    v[3] = f2bf(xb[(size_t)(ci0+3)*NPIX]);
    int cc = ci0 >> 6;
    *(u16x4*)(xT + (((size_t)(b*2+cc)*NPIX + px)*64 + (ci0 & 63))) = v;
  }
}

// Dilated 3x3 conv (dil=3,pad=3) + BN + exact GELU via bf16 MFMA implicit GEMM.
// 16x16 output tile, all 64 couts. Staging: global_load_lds from xT with
// pre-swizzled source granules (linear LDS dest); border blocks take reg path.
__global__ __launch_bounds__(256) void k_conv(const unsigned short* __restrict__ xT,
    const unsigned short* __restrict__ wP,
    const float* __restrict__ bg, const float* __restrict__ bbeta,
    const float* __restrict__ bm, const float* __restrict__ bv,
    float* __restrict__ feat){
  __shared__ __align__(16) unsigned short sX[4096*8];   // 512 px x 64 ci bf16 (484 used)
  const int tid = threadIdx.x;
  const int bb = blockIdx.z;
  const int x0 = blockIdx.x * 16, y0 = blockIdx.y * 16;
  const int wv  = tid >> 6;
  const int l   = tid & 63;
  const int l15 = l & 15;
  const int g   = l >> 4;

  const bool interior = (x0 >= 16) && (x0 <= 96) && (y0 >= 16) && (y0 <= 96);

  f32x4 acc[4][4];
  #pragma unroll
  for (int m=0;m<4;++m)
    #pragma unroll
    for (int n=0;n<4;++n) acc[m][n] = {0.f,0.f,0.f,0.f};

  for (int cc = 0; cc < 2; ++cc) {
    __syncthreads();
    const unsigned short* xcc = xT + ((size_t)(bb*2 + cc))*NPIX*64;
    if (interior) {
      #pragma unroll
      for (int k = 0; k < 16; ++k) {
        int blk = k*4 + wv;               // 64-granule block, wave-uniform
        int idx = blk*64 + l;             // granule id (16B each)
        int p = idx >> 3, gr = idx & 7;
        int pc = p < 484 ? p : 483;
        int py = pc / 22, px = pc - py*22;
        int gpix = (y0-3+py)*128 + (x0-3+px);
        int sg = gr ^ (p & 7);
        const unsigned short* srcp = xcc + (size_t)gpix*64 + sg*8;
        gload_lds16(srcp, (char*)sX + blk*1024);
      }
    } else {
      #pragma unroll
      for (int k = 0; k < 16; ++k) {
        int idx = k*256 + tid;
        int p = idx >> 3, gr = idx & 7;
        u16x8 v = {0,0,0,0,0,0,0,0};
        if (p < 484) {
          int py = p / 22, px = p - py*22;
          int gy = y0-3+py, gx = x0-3+px;
          if ((unsigned)gy < 128u && (unsigned)gx < 128u) {
            int sg = gr ^ (p & 7);
            v = *(const u16x8*)(xcc + (size_t)(gy*128+gx)*64 + sg*8);
          }
        }
        *(u16x8*)((char*)sX + idx*16) = v;
      }
    }
    __syncthreads();

    const unsigned short* wcc = wP + cc*36864;
    for (int tap = 0; tap < 9; ++tap) {
      int dy = (tap/3)*3, dx = (tap - (tap/3)*3)*3;
      const unsigned short* wt = wcc + tap*4096;
      #pragma unroll
      for (int kc = 0; kc < 2; ++kc) {
        bf16x8 a[4], b[4];
        int ko = kc*32 + g*8;
        #pragma unroll
        for (int m = 0; m < 4; ++m)
          a[m] = *reinterpret_cast<const bf16x8*>(wt + (m*16 + l15)*64 + ko);
        #pragma unroll
        for (int n = 0; n < 4; ++n) {
          int p = (wv*4 + n + dy)*22 + l15 + dx;
          b[n] = *reinterpret_cast<const bf16x8*>(&sX[p*64 + (ko ^ ((p & 7) << 3))]);
        }
        #pragma unroll
        for (int m = 0; m < 4; ++m)
          #pragma unroll
          for (int n = 0; n < 4; ++n)
            acc[m][n] = __builtin_amdgcn_mfma_f32_16x16x32_bf16(a[m], b[n], acc[m][n], 0, 0, 0);
      }
    }
  }

  #pragma unroll
  for (int m = 0; m < 4; ++m) {
    #pragma unroll
    for (int r = 0; r < 4; ++r) {
      int co = m*16 + g*4 + r;
      float sc = bg[co] * rsqrtf(bv[co] + 1e-5f);
      float sh = bbeta[co] - bm[co]*sc;
      #pragma unroll
      for (int n = 0; n < 4; ++n) {
        int py = wv*4 + n;
        float v = acc[m][n][r]*sc + sh;
        feat[((size_t)(bb*CDN + co)*128 + (y0+py))*128 + x0 + l15] = gelu_exact(v);
      }
    }
  }
}

// Per (b,h): 8x8 spatial Gram -> attention via Plancherel, softmax rows.
__global__ __launch_bounds__(256) void k_attn(const float* __restrict__ feat, const float* __restrict__ tau,
                                              float* __restrict__ attn){
  int bh = blockIdx.x; int b = bh >> 3, h = bh & 7;
  const float* f = feat + (size_t)(b*CDN + h*HDIM)*NPIX;
  float acc[36];
  #pragma unroll
  for (int i=0;i<36;++i) acc[i]=0.f;
  for (int p = threadIdx.x; p < NPIX; p += 256) {
    float v[8];
    #pragma unroll
    for (int d=0; d<8; ++d) v[d] = f[d*NPIX + p];
    int i = 0;
    #pragma unroll
    for (int d=0; d<8; ++d)
      #pragma unroll
      for (int e=0; e<=d; ++e) acc[i++] += v[d]*v[e];
  }
  #pragma unroll
  for (int i=0;i<36;++i)
    #pragma unroll
    for (int off=32; off; off>>=1) acc[i] += __shfl_xor(acc[i], off, 64);
  __shared__ float red[4][36];
  int wave = threadIdx.x >> 6, lane = threadIdx.x & 63;
  if (lane == 0) {
    #pragma unroll
    for (int i=0;i<36;++i) red[wave][i] = acc[i];
  }
  __syncthreads();
  if (threadIdx.x == 0) {
    float G[8][8];
    int i=0;
    for (int d=0;d<8;++d) for(int e=0;e<=d;++e){
      float s = red[0][i]+red[1][i]+red[2][i]+red[3][i];
      G[d][e]=s; G[e][d]=s; ++i;
    }
    float nrm[8];
    for (int d=0;d<8;++d) nrm[d] = sqrtf(16384.f*G[d][d] + 1e-6f);
    float tv = tau[h];
    for (int d=0;d<8;++d) {
      float row[8]; float mx = -1e30f;
      for (int e=0;e<8;++e){ row[e] = tv*16384.f*G[d][e]/(nrm[d]*nrm[e]); mx = fmaxf(mx,row[e]); }
      float s=0.f;
      for (int e=0;e<8;++e){ row[e] = expf(row[e]-mx); s += row[e]; }
      for (int e=0;e<8;++e) attn[bh*64 + d*8 + e] = row[e]/s;
    }
  }
}

// out_f = sqrt((attn @ feat)^2 + (mean_e feat)^2) + x   (channels 0..63)
__global__ __launch_bounds__(256) void k_outf(const float* __restrict__ feat, const float* __restrict__ attn,
                                              const float* __restrict__ x, float* __restrict__ out){
  int bh = blockIdx.x; int b = bh >> 3, h = bh & 7;
  int p = blockIdx.y*256 + threadIdx.x;
  __shared__ float A[64];
  if (threadIdx.x < 64) A[threadIdx.x] = attn[bh*64 + threadIdx.x];
  __syncthreads();
  const float* f = feat + (size_t)(b*CDN + h*HDIM)*NPIX;
  float v[8];
  #pragma unroll
  for (int e=0;e<8;++e) v[e] = f[e*NPIX + p];
  float im = 0.f;
  #pragma unroll
  for (int e=0;e<8;++e) im += v[e];
  im *= 0.125f;
  #pragma unroll
  for (int d=0;d<8;++d){
    float re = 0.f;
    #pragma unroll
    for (int e=0;e<8;++e) re += A[d*8+e]*v[e];
    size_t o = ((size_t)(b*CIN + h*HDIM + d))*NPIX + p;
    out[o] = sqrtf(re*re + im*im) + x[o];
  }
}

#define TSTR 129
// row FFT over x + transposed write: feat -> G[b][c][sx][y] (y-contiguous)
__global__ __launch_bounds__(256) void k_fftA(const float* __restrict__ feat, c2* __restrict__ G){
  __shared__ c2 T[128*TSTR];   // 132,096 B
  int ib = blockIdx.x;         // b*64+c
  int wv = threadIdx.x >> 6, t = threadIdx.x & 63;
  Tw w; tw_init(w, t);
  const float* src = feat + (size_t)ib*NPIX;
  for (int r0 = wv; r0 < 128; r0 += 8) {
    int r1 = r0 + 4;
    c2 a0 = {src[r0*128 + t], 0.f}, b0 = {src[r0*128 + t + 64], 0.f};
    c2 a1 = {src[r1*128 + t], 0.f}, b1 = {src[r1*128 + t + 64], 0.f};
    fft128_fwd(a0,b0,t,w);
    fft128_fwd(a1,b1,t,w);
    T[r0*TSTR + t] = a0; T[r0*TSTR + t + 64] = b0;
    T[r1*TSTR + t] = a1; T[r1*TSTR + t + 64] = b1;
  }
  __syncthreads();
  c2* dst = G + (size_t)ib*NPIX;
  for (int i = 0; i < 32; ++i) {
    int s = wv*32 + i;
    c2 lo = T[t*TSTR + s];
    c2 hi = T[(t+64)*TSTR + s];
    dst[(size_t)s*128 + t]      = lo;
    dst[(size_t)s*128 + t + 64] = hi;
  }
}

#define GSTR 129
// col FFT over y + channel-mix gate + inverse col FFT, in place on G. One block per (b, sx).
__global__ __launch_bounds__(256) void k_gateB(c2* __restrict__ G,
    const float* __restrict__ w1, const float* __restrict__ b1,
    const float* __restrict__ gg, const float* __restrict__ gbeta,
    const float* __restrict__ gm, const float* __restrict__ gv,
    const float* __restrict__ w2, const float* __restrict__ b2){
  __shared__ c2 S[64*GSTR];    // 66,048 B
  int b = blockIdx.x >> 7, sx = blockIdx.x & 127;
  int tid = threadIdx.x, wv = tid >> 6, t = tid & 63;
  Tw w; tw_init(w, t);
  c2* base = G + (size_t)b*CDN*NPIX + (size_t)sx*128;
  #pragma unroll
  for (int k = 0; k < 16; ++k) {
    int idx = k*256 + tid;            // 16B granule
    int ch = idx >> 6, gp = idx & 63;
    const c2* gsrc = base + (size_t)ch*NPIX + gp*2;
    c2 v0 = gsrc[0], v1 = gsrc[1];
    S[ch*GSTR + gp*2]     = v0;
    S[ch*GSTR + gp*2 + 1] = v1;
  }
  __syncthreads();
  for (int c0 = wv; c0 < 64; c0 += 8) {
    int c1 = c0 + 4;
    c2 a0 = S[c0*GSTR + t], b0 = S[c0*GSTR + t + 64];
    c2 a1 = S[c1*GSTR + t], b1 = S[c1*GSTR + t + 64];
    fft128_fwd(a0,b0,t,w);
    fft128_fwd(a1,b1,t,w);
    S[c0*GSTR + t] = a0; S[c0*GSTR + t + 64] = b0;
    S[c1*GSTR + t] = a1; S[c1*GSTR + t + 64] = b1;
  }
  __syncthreads();
  if (tid < 128) {
    int sy = tid;
    float m0 = b1[0], m1 = b1[1], m2 = b1[2], m3 = b1[3];
    for (int ch = 0; ch < 64; ++ch) {
      float re = S[ch*GSTR + sy].x;
      m0 += w1[0*64+ch]*re; m1 += w1[1*64+ch]*re;
      m2 += w1[2*64+ch]*re; m3 += w1[3*64+ch]*re;
    }
    float mid[4] = {m0,m1,m2,m3};
    #pragma unroll
    for (int m = 0; m < 4; ++m) {
      float sc = gg[m]*rsqrtf(gv[m]+1e-5f);
      float sh = gbeta[m] - gm[m]*sc;
      mid[m] = gelu_exact(mid[m]*sc + sh);
    }
    for (int ch = 0; ch < 64; ++ch) {
      float s = b2[ch] + w2[ch*4+0]*mid[0] + w2[ch*4+1]*mid[1]
                       + w2[ch*4+2]*mid[2] + w2[ch*4+3]*mid[3];
      s = 1.f/(1.f+expf(-s));
      c2 v = S[ch*GSTR + sy];
      v.x *= s; v.y *= s;
      S[ch*GSTR + sy] = v;
    }
  }
  __syncthreads();
  for (int c0 = wv; c0 < 64; c0 += 8) {
    int c1 = c0 + 4;
    c2 a0 = S[c0*GSTR + t], b0 = S[c0*GSTR + t + 64];
    c2 a1 = S[c1*GSTR + t], b1 = S[c1*GSTR + t + 64];
    fft128_inv(a0,b0,t,w);
    fft128_inv(a1,b1,t,w);
    c2* g0 = base + (size_t)c0*NPIX;
    c2* g1 = base + (size_t)c1*NPIX;
    g0[t] = a0; g0[t+64] = b0;
    g1[t] = a1; g1[t+64] = b1;
  }
}

// inverse row FFT over sx + abs + residual -> out channels 64..127
__global__ __launch_bounds__(256) void k_fftC(const c2* __restrict__ G, const float* __restrict__ x,
                                              float* __restrict__ out){
  __shared__ c2 T[128*TSTR];
  int ib = blockIdx.x;          // b*64+c
  int b = ib >> 6, c = ib & 63;
  int tid = threadIdx.x, wv = tid >> 6, t = tid & 63;
  Tw w; tw_init(w, t);
  const c2* src = G + (size_t)ib*NPIX;
  #pragma unroll
  for (int k = 0; k < 32; ++k) {
    int idx = k*256 + tid;           // 16B granule
    int sx = idx >> 6, gp = idx & 63;
    c2 v0 = src[(size_t)sx*128 + gp*2];
    c2 v1 = src[(size_t)sx*128 + gp*2 + 1];
    T[sx*TSTR + gp*2]     = v0;
    T[sx*TSTR + gp*2 + 1] = v1;
  }
  __syncthreads();
  const float* xr = x + ((size_t)(b*CIN + 64 + c))*NPIX;
  float* orow = out + ((size_t)(b*CIN + 64 + c))*NPIX;
  const float sc = 1.f/16384.f;
  for (int y0 = wv; y0 < 128; y0 += 8) {
    int y1 = y0 + 4;
    c2 a0 = T[t*TSTR + y0], b0 = T[(t+64)*TSTR + y0];
    c2 a1 = T[t*TSTR + y1], b1 = T[(t+64)*TSTR + y1];
    fft128_inv(a0,b0,t,w);
    fft128_inv(a1,b1,t,w);
    orow[y0*128 + t]      = sqrtf(a0.x*a0.x + a0.y*a0.y)*sc + xr[y0*128 + t];
    orow[y0*128 + t + 64] = sqrtf(b0.x*b0.x + b0.y*b0.y)*sc + xr[y0*128 + t + 64];
    orow[y1*128 + t]      = sqrtf(a1.x*a1.x + a1.y*a1.y)*sc + xr[y1*128 + t];
    orow[y1*128 + t + 64] = sqrtf(b1.x*b1.x + b1.y*b1.y)*sc + xr[y1*128 + t + 64];
  }
}

extern "C" void kernel_launch(void* const* d_in, const int* in_sizes, int n_in,
                              void* d_out, int out_size, void* d_ws, size_t ws_size,
                              hipStream_t stream){
  const float* x      = (const float*)d_in[0];
  const float* conv_w = (const float*)d_in[1];
  const float* bn1_g  = (const float*)d_in[2];
  const float* bn1_b  = (const float*)d_in[3];
  const float* bn1_m  = (const float*)d_in[4];
  const float* bn1_v  = (const float*)d_in[5];
  const float* cg1_w  = (const float*)d_in[6];
  const float* cg1_b  = (const float*)d_in[7];
  const float* cgbn_g = (const float*)d_in[8];
  const float* cgbn_b = (const float*)d_in[9];
  const float* cgbn_m = (const float*)d_in[10];
  const float* cgbn_v = (const float*)d_in[11];
  const float* cg2_w  = (const float*)d_in[12];
  const float* cg2_b  = (const float*)d_in[13];
  const float* tau    = (const float*)d_in[14];
  float* out = (float*)d_out;

  char* ws = (char*)d_ws;
  float*          feat  = (float*)ws;                           // [0, 33.5M)
  unsigned short* xT    = (unsigned short*)(ws + 33554432);     // [33.5M, 67M), dead after k_conv
  c2*             G     = (c2*)(ws + 33554432);                 // [33.5M, 100.5M) aliases xT (safe)
  unsigned short* wPack = (unsigned short*)(ws + 100663296);    // 147,456 B
  float*          attn  = (float*)(ws + 100663296 + 147456);    // 16,384 B

  k_wpack<<<288, 256, 0, stream>>>(conv_w, wPack);
  k_xpose<<<512, 256, 0, stream>>>(x, xT);
  k_conv<<<dim3(8,8,NB), 256, 0, stream>>>(xT, wPack, bn1_g, bn1_b, bn1_m, bn1_v, feat);
  k_attn<<<NB*NHEADS, 256, 0, stream>>>(feat, tau, attn);
  k_outf<<<dim3(NB*NHEADS, 64), 256, 0, stream>>>(feat, attn, x, out);
  k_fftA<<<NB*CDN, 256, 0, stream>>>(feat, G);
  k_gateB<<<NB*128, 256, 0, stream>>>(G, cg1_w, cg1_b, cgbn_g, cgbn_b, cgbn_m, cgbn_v, cg2_w, cg2_b);
  k_fftC<<<NB*CDN, 256, 0, stream>>>(G, x, out);
}

// Round 4
// 339.278 us; speedup vs baseline: 1.7359x; 1.0473x over previous
//
#include <hip/hip_runtime.h>
#include <hip/hip_bf16.h>
#include <math.h>

#define NB 8
#define CIN 128
#define CDN 64
#define NPIX 16384            // 128*128
#define NHEADS 8
#define HDIM 8

typedef __attribute__((ext_vector_type(8))) short bf16x8;
typedef __attribute__((ext_vector_type(4))) float f32x4;
typedef __attribute__((ext_vector_type(8))) unsigned short u16x8;
typedef __attribute__((ext_vector_type(4))) unsigned short u16x4;

struct alignas(8) c2 { float x, y; };

__device__ inline c2 cadd(c2 a, c2 b){ return {a.x+b.x, a.y+b.y}; }
__device__ inline c2 csub(c2 a, c2 b){ return {a.x-b.x, a.y-b.y}; }
__device__ inline c2 cmul(c2 a, c2 b){ return {a.x*b.x - a.y*b.y, a.x*b.y + a.y*b.x}; }
__device__ inline c2 shfl2(c2 v, int m){ return { __shfl_xor(v.x, m, 64), __shfl_xor(v.y, m, 64) }; }
__device__ inline float gelu_exact(float v){ return 0.5f*v*(1.f + erff(v*0.70710678118654752f)); }
__device__ inline unsigned short f2bf(float f){
  __hip_bfloat16 h = __float2bfloat16(f);
  return *reinterpret_cast<unsigned short*>(&h);
}

// ---- twiddle-hoisted 128-pt wave FFT: lane t holds positions t and t+64 ----
struct Tw { c2 t0; c2 t[6]; };
__device__ inline void tw_init(Tw& w, int t){
  float sn, cs;
  sincosf(-6.283185307179586f * (float)t * (1.f/128.f), &sn, &cs); w.t0 = {cs, sn};
  #pragma unroll
  for (int i = 0; i < 6; ++i) {
    int sp = 32 >> i;
    int j = t & (sp-1);
    sincosf(-3.141592653589793f * (float)j / (float)sp, &sn, &cs);
    w.t[i] = {cs, sn};
  }
}
// forward DIF: natural in -> slot order out
__device__ inline void fft128_fwd(c2& a, c2& b, int t, const Tw& w){
  c2 s = cadd(a,b), d = csub(a,b);
  a = s; b = cmul(d, w.t0);
  #pragma unroll
  for (int i = 0; i < 6; ++i) {
    int sp = 32 >> i;
    c2 oa = shfl2(a, sp), ob = shfl2(b, sp);
    c2 tw = w.t[i];
    if (t & sp) { a = cmul(csub(oa,a), tw); b = cmul(csub(ob,b), tw); }
    else        { a = cadd(a,oa);           b = cadd(b,ob); }
  }
}
// inverse DIT (no scaling): slot order in -> natural out
__device__ inline void fft128_inv(c2& a, c2& b, int t, const Tw& w){
  #pragma unroll
  for (int i = 5; i >= 0; --i) {
    int sp = 32 >> i;
    c2 tw = {w.t[i].x, -w.t[i].y};
    c2 oa = shfl2(a, sp), ob = shfl2(b, sp);
    if (t & sp) { a = csub(oa, cmul(a, tw)); b = csub(ob, cmul(b, tw)); }
    else        { a = cadd(a, cmul(oa, tw)); b = cadd(b, cmul(ob, tw)); }
  }
  c2 t0c = {w.t0.x, -w.t0.y};
  c2 wb = cmul(b, t0c);
  b = csub(a, wb);
  a = cadd(a, wb);
}

__device__ inline void gload_lds16(const void* g, void* l){
  __builtin_amdgcn_global_load_lds(
      (const __attribute__((address_space(1))) unsigned int*)g,
      (__attribute__((address_space(3))) unsigned int*)l, 16, 0, 0);
}

// conv_w fp32 [64co][128ci][3][3] -> wPack bf16 [cc=2][tap=9][co=64][ci=64]
__global__ __launch_bounds__(256) void k_wpack(const float* __restrict__ w, unsigned short* __restrict__ wP){
  int idx = blockIdx.x*256 + threadIdx.x;
  if (idx >= 2*9*64*64) return;
  int cc  = idx / 36864;
  int r   = idx - cc*36864;
  int tap = r / 4096;
  int r2  = r - tap*4096;
  int co  = r2 >> 6;
  int cil = r2 & 63;
  int ci  = cc*64 + cil;
  wP[idx] = f2bf(w[(co*CIN + ci)*9 + tap]);
}

// x fp32 [b][128ci][16384p] -> xT bf16 [b][2cc][16384p][64ci]
__global__ __launch_bounds__(256) void k_xpose(const float* __restrict__ x, unsigned short* __restrict__ xT){
  int b = blockIdx.x >> 6;
  int px = (blockIdx.x & 63)*256 + threadIdx.x;
  const float* xb = x + (size_t)b*CIN*NPIX + px;
  #pragma unroll 2
  for (int ci0 = 0; ci0 < 128; ci0 += 8) {
    u16x8 v;
    #pragma unroll
    for (int j = 0; j < 8; ++j) v[j] = f2bf(xb[(size_t)(ci0+j)*NPIX]);
    int cc = ci0 >> 6;
    *(u16x8*)(xT + (((size_t)(b*2+cc)*NPIX + px)*64 + (ci0 & 63))) = v;
  }
}

// Dilated 3x3 conv (dil=3,pad=3) + BN + exact GELU via bf16 MFMA implicit GEMM.
__global__ __launch_bounds__(256) void k_conv(const unsigned short* __restrict__ xT,
    const unsigned short* __restrict__ wP,
    const float* __restrict__ bg, const float* __restrict__ bbeta,
    const float* __restrict__ bm, const float* __restrict__ bv,
    float* __restrict__ feat){
  __shared__ __align__(16) unsigned short sX[4096*8];   // 512 px x 64 ci bf16 (484 used)
  const int tid = threadIdx.x;
  const int bb = blockIdx.z;
  const int x0 = blockIdx.x * 16, y0 = blockIdx.y * 16;
  const int wv  = tid >> 6;
  const int l   = tid & 63;
  const int l15 = l & 15;
  const int g   = l >> 4;

  const bool interior = (x0 >= 16) && (x0 <= 96) && (y0 >= 16) && (y0 <= 96);

  f32x4 acc[4][4];
  #pragma unroll
  for (int m=0;m<4;++m)
    #pragma unroll
    for (int n=0;n<4;++n) acc[m][n] = {0.f,0.f,0.f,0.f};

  for (int cc = 0; cc < 2; ++cc) {
    __syncthreads();
    const unsigned short* xcc = xT + ((size_t)(bb*2 + cc))*NPIX*64;
    if (interior) {
      #pragma unroll
      for (int k = 0; k < 16; ++k) {
        int blk = k*4 + wv;
        int idx = blk*64 + l;
        int p = idx >> 3, gr = idx & 7;
        int pc = p < 484 ? p : 483;
        int py = pc / 22, px = pc - py*22;
        int gpix = (y0-3+py)*128 + (x0-3+px);
        int sg = gr ^ (p & 7);
        const unsigned short* srcp = xcc + (size_t)gpix*64 + sg*8;
        gload_lds16(srcp, (char*)sX + blk*1024);
      }
    } else {
      #pragma unroll
      for (int k = 0; k < 16; ++k) {
        int idx = k*256 + tid;
        int p = idx >> 3, gr = idx & 7;
        u16x8 v = {0,0,0,0,0,0,0,0};
        if (p < 484) {
          int py = p / 22, px = p - py*22;
          int gy = y0-3+py, gx = x0-3+px;
          if ((unsigned)gy < 128u && (unsigned)gx < 128u) {
            int sg = gr ^ (p & 7);
            v = *(const u16x8*)(xcc + (size_t)(gy*128+gx)*64 + sg*8);
          }
        }
        *(u16x8*)((char*)sX + idx*16) = v;
      }
    }
    __syncthreads();

    const unsigned short* wcc = wP + cc*36864;
    for (int tap = 0; tap < 9; ++tap) {
      int dy = (tap/3)*3, dx = (tap - (tap/3)*3)*3;
      const unsigned short* wt = wcc + tap*4096;
      #pragma unroll
      for (int kc = 0; kc < 2; ++kc) {
        bf16x8 a[4], b[4];
        int ko = kc*32 + g*8;
        #pragma unroll
        for (int m = 0; m < 4; ++m)
          a[m] = *reinterpret_cast<const bf16x8*>(wt + (m*16 + l15)*64 + ko);
        #pragma unroll
        for (int n = 0; n < 4; ++n) {
          int p = (wv*4 + n + dy)*22 + l15 + dx;
          b[n] = *reinterpret_cast<const bf16x8*>(&sX[p*64 + (ko ^ ((p & 7) << 3))]);
        }
        #pragma unroll
        for (int m = 0; m < 4; ++m)
          #pragma unroll
          for (int n = 0; n < 4; ++n)
            acc[m][n] = __builtin_amdgcn_mfma_f32_16x16x32_bf16(a[m], b[n], acc[m][n], 0, 0, 0);
      }
    }
  }

  #pragma unroll
  for (int m = 0; m < 4; ++m) {
    #pragma unroll
    for (int r = 0; r < 4; ++r) {
      int co = m*16 + g*4 + r;
      float sc = bg[co] * rsqrtf(bv[co] + 1e-5f);
      float sh = bbeta[co] - bm[co]*sc;
      #pragma unroll
      for (int n = 0; n < 4; ++n) {
        int py = wv*4 + n;
        float v = acc[m][n][r]*sc + sh;
        feat[((size_t)(bb*CDN + co)*128 + (y0+py))*128 + x0 + l15] = gelu_exact(v);
      }
    }
  }
}

// stage 1: partial 8x8 Gram over 2048-pixel chunks -> part[bh*8+ck][36]
__global__ __launch_bounds__(256) void k_attn1(const float* __restrict__ feat, float* __restrict__ part){
  int bh = blockIdx.x, ck = blockIdx.y;
  int b = bh >> 3, h = bh & 7;
  const float* f = feat + (size_t)(b*CDN + h*HDIM)*NPIX;
  float acc[36];
  #pragma unroll
  for (int i=0;i<36;++i) acc[i]=0.f;
  for (int p = ck*2048 + threadIdx.x; p < (ck+1)*2048; p += 256) {
    float v[8];
    #pragma unroll
    for (int d=0; d<8; ++d) v[d] = f[d*NPIX + p];
    int i = 0;
    #pragma unroll
    for (int d=0; d<8; ++d)
      #pragma unroll
      for (int e=0; e<=d; ++e) acc[i++] += v[d]*v[e];
  }
  #pragma unroll
  for (int i=0;i<36;++i)
    #pragma unroll
    for (int off=32; off; off>>=1) acc[i] += __shfl_xor(acc[i], off, 64);
  __shared__ float red[4][36];
  int wave = threadIdx.x >> 6, lane = threadIdx.x & 63;
  if (lane == 0) {
    #pragma unroll
    for (int i=0;i<36;++i) red[wave][i] = acc[i];
  }
  __syncthreads();
  if (threadIdx.x < 36)
    part[(bh*8+ck)*36 + threadIdx.x] =
      red[0][threadIdx.x]+red[1][threadIdx.x]+red[2][threadIdx.x]+red[3][threadIdx.x];
}

// stage 2: reduce partials, build softmax'd attention matrix
__global__ __launch_bounds__(64) void k_attn2(const float* __restrict__ part, const float* __restrict__ tau,
                                              float* __restrict__ attn){
  int bh = blockIdx.x; int h = bh & 7;
  __shared__ float Gm[36];
  int i = threadIdx.x;
  if (i < 36) {
    float s = 0.f;
    #pragma unroll
    for (int k = 0; k < 8; ++k) s += part[(bh*8+k)*36 + i];
    Gm[i] = s;
  }
  __syncthreads();
  if (i == 0) {
    float G[8][8];
    int c=0;
    for (int d=0;d<8;++d) for(int e=0;e<=d;++e){
      float s = Gm[c]; G[d][e]=s; G[e][d]=s; ++c;
    }
    float nrm[8];
    for (int d=0;d<8;++d) nrm[d] = sqrtf(16384.f*G[d][d] + 1e-6f);
    float tv = tau[h];
    for (int d=0;d<8;++d) {
      float row[8]; float mx = -1e30f;
      for (int e=0;e<8;++e){ row[e] = tv*16384.f*G[d][e]/(nrm[d]*nrm[e]); mx = fmaxf(mx,row[e]); }
      float s=0.f;
      for (int e=0;e<8;++e){ row[e] = expf(row[e]-mx); s += row[e]; }
      for (int e=0;e<8;++e) attn[bh*64 + d*8 + e] = row[e]/s;
    }
  }
}

// out_f = sqrt((attn @ feat)^2 + (mean_e feat)^2) + x   (channels 0..63)
__global__ __launch_bounds__(256) void k_outf(const float* __restrict__ feat, const float* __restrict__ attn,
                                              const float* __restrict__ x, float* __restrict__ out){
  int bh = blockIdx.x; int b = bh >> 3, h = bh & 7;
  int p = blockIdx.y*256 + threadIdx.x;
  __shared__ float A[64];
  if (threadIdx.x < 64) A[threadIdx.x] = attn[bh*64 + threadIdx.x];
  __syncthreads();
  const float* f = feat + (size_t)(b*CDN + h*HDIM)*NPIX;
  float v[8];
  #pragma unroll
  for (int e=0;e<8;++e) v[e] = f[e*NPIX + p];
  float im = 0.f;
  #pragma unroll
  for (int e=0;e<8;++e) im += v[e];
  im *= 0.125f;
  #pragma unroll
  for (int d=0;d<8;++d){
    float re = 0.f;
    #pragma unroll
    for (int e=0;e<8;++e) re += A[d*8+e]*v[e];
    size_t o = ((size_t)(b*CIN + h*HDIM + d))*NPIX + p;
    out[o] = sqrtf(re*re + im*im) + x[o];
  }
}

#define TASTR 129
// row FFT over x + transposed write: feat -> G[b][c][sx][y], 32-row chunks (33KB LDS)
__global__ __launch_bounds__(256) void k_fftA(const float* __restrict__ feat, c2* __restrict__ G){
  __shared__ c2 T[32*TASTR];
  int ib = blockIdx.x;
  int tid = threadIdx.x, wv = tid >> 6, t = tid & 63;
  Tw w; tw_init(w, t);
  const float* src = feat + (size_t)ib*NPIX;
  c2* dst = G + (size_t)ib*NPIX;
  int yl = t & 31, sh = t >> 5;
  for (int k = 0; k < 4; ++k) {
    if (k) __syncthreads();
    #pragma unroll 2
    for (int i = 0; i < 8; ++i) {
      int rl = wv*8 + i;
      int r = k*32 + rl;
      c2 a = {src[r*128 + t], 0.f};
      c2 b = {src[r*128 + t + 64], 0.f};
      fft128_fwd(a, b, t, w);
      T[rl*TASTR + t] = a;
      T[rl*TASTR + t + 64] = b;
    }
    __syncthreads();
    #pragma unroll 4
    for (int j = 0; j < 16; ++j) {
      int s = wv*32 + j*2 + sh;
      c2 v = T[yl*TASTR + s];
      dst[(size_t)s*128 + k*32 + yl] = v;
    }
  }
}

// col FFT + gate + inverse col FFT, fully in registers. One block per (b, sx).
// Wave wv holds channels wv*16..wv*16+15; lane t holds y=t and y=t+64.
__global__ __launch_bounds__(256) void k_gateB(c2* __restrict__ G,
    const float* __restrict__ w1, const float* __restrict__ b1,
    const float* __restrict__ gg, const float* __restrict__ gbeta,
    const float* __restrict__ gm, const float* __restrict__ gv,
    const float* __restrict__ w2, const float* __restrict__ b2){
  __shared__ float P[128*17];   // 8704 B: [sy][wv*4+m]
  int b = blockIdx.x >> 7, sx = blockIdx.x & 127;
  int tid = threadIdx.x, wv = tid >> 6, t = tid & 63;
  Tw w; tw_init(w, t);
  c2* base = G + (size_t)b*CDN*NPIX + (size_t)sx*128;
  c2 d0[16], d1[16];
  #pragma unroll
  for (int i = 0; i < 16; ++i) {
    const c2* g = base + (size_t)(wv*16 + i)*NPIX;
    d0[i] = g[t]; d1[i] = g[t+64];
  }
  #pragma unroll 2
  for (int i = 0; i < 16; ++i) fft128_fwd(d0[i], d1[i], t, w);
  // per-wave partial mid sums at sy=t and sy=t+64
  float pm0[4] = {0,0,0,0}, pm1[4] = {0,0,0,0};
  #pragma unroll
  for (int i = 0; i < 16; ++i) {
    int ch = wv*16 + i;
    #pragma unroll
    for (int m = 0; m < 4; ++m) {
      float wc = w1[m*64+ch];
      pm0[m] += wc * d0[i].x;
      pm1[m] += wc * d1[i].x;
    }
  }
  #pragma unroll
  for (int m = 0; m < 4; ++m) {
    P[t*17 + wv*4 + m] = pm0[m];
    P[(t+64)*17 + wv*4 + m] = pm1[m];
  }
  __syncthreads();
  float mid0[4], mid1[4];
  #pragma unroll
  for (int m = 0; m < 4; ++m) {
    float s0 = b1[m], s1 = b1[m];
    #pragma unroll
    for (int k = 0; k < 4; ++k) { s0 += P[t*17 + k*4 + m]; s1 += P[(t+64)*17 + k*4 + m]; }
    float sc = gg[m]*rsqrtf(gv[m]+1e-5f);
    float sh = gbeta[m] - gm[m]*sc;
    mid0[m] = gelu_exact(s0*sc + sh);
    mid1[m] = gelu_exact(s1*sc + sh);
  }
  #pragma unroll
  for (int i = 0; i < 16; ++i) {
    int ch = wv*16 + i;
    float g0 = b2[ch], g1 = g0;
    #pragma unroll
    for (int m = 0; m < 4; ++m) { float wc = w2[ch*4+m]; g0 += wc*mid0[m]; g1 += wc*mid1[m]; }
    g0 = 1.f/(1.f+expf(-g0)); g1 = 1.f/(1.f+expf(-g1));
    d0[i].x *= g0; d0[i].y *= g0;
    d1[i].x *= g1; d1[i].y *= g1;
  }
  #pragma unroll 2
  for (int i = 0; i < 16; ++i) fft128_inv(d0[i], d1[i], t, w);
  #pragma unroll
  for (int i = 0; i < 16; ++i) {
    c2* g = base + (size_t)(wv*16 + i)*NPIX;
    g[t] = d0[i]; g[t+64] = d1[i];
  }
}

// inverse row FFT over sx + abs + residual -> out channels 64..127, 32-y chunks
__global__ __launch_bounds__(256) void k_fftC(const c2* __restrict__ G, const float* __restrict__ x,
                                              float* __restrict__ out){
  __shared__ c2 T[32*TASTR];
  int ib = blockIdx.x;          // b*64+c
  int b = ib >> 6, c = ib & 63;
  int tid = threadIdx.x, wv = tid >> 6, t = tid & 63;
  Tw w; tw_init(w, t);
  const c2* src = G + (size_t)ib*NPIX;
  const float* xr = x + ((size_t)(b*CIN + 64 + c))*NPIX;
  float* orow = out + ((size_t)(b*CIN + 64 + c))*NPIX;
  const float sc = 1.f/16384.f;
  int yl = t & 31, sh = t >> 5;
  for (int k = 0; k < 4; ++k) {
    if (k) __syncthreads();
    #pragma unroll 4
    for (int j = 0; j < 16; ++j) {
      int s = wv*32 + j*2 + sh;
      c2 v = src[(size_t)s*128 + k*32 + yl];
      T[yl*TASTR + s] = v;
    }
    __syncthreads();
    #pragma unroll 2
    for (int i = 0; i < 8; ++i) {
      int yl2 = wv*8 + i;
      int y = k*32 + yl2;
      c2 a = T[yl2*TASTR + t];
      c2 bb = T[yl2*TASTR + t + 64];
      fft128_inv(a, bb, t, w);
      orow[y*128 + t]      = sqrtf(a.x*a.x + a.y*a.y)*sc + xr[y*128 + t];
      orow[y*128 + t + 64] = sqrtf(bb.x*bb.x + bb.y*bb.y)*sc + xr[y*128 + t + 64];
    }
  }
}

extern "C" void kernel_launch(void* const* d_in, const int* in_sizes, int n_in,
                              void* d_out, int out_size, void* d_ws, size_t ws_size,
                              hipStream_t stream){
  const float* x      = (const float*)d_in[0];
  const float* conv_w = (const float*)d_in[1];
  const float* bn1_g  = (const float*)d_in[2];
  const float* bn1_b  = (const float*)d_in[3];
  const float* bn1_m  = (const float*)d_in[4];
  const float* bn1_v  = (const float*)d_in[5];
  const float* cg1_w  = (const float*)d_in[6];
  const float* cg1_b  = (const float*)d_in[7];
  const float* cgbn_g = (const float*)d_in[8];
  const float* cgbn_b = (const float*)d_in[9];
  const float* cgbn_m = (const float*)d_in[10];
  const float* cgbn_v = (const float*)d_in[11];
  const float* cg2_w  = (const float*)d_in[12];
  const float* cg2_b  = (const float*)d_in[13];
  const float* tau    = (const float*)d_in[14];
  float* out = (float*)d_out;

  char* ws = (char*)d_ws;
  float*          feat  = (float*)ws;                           // [0, 33.5M)
  unsigned short* xT    = (unsigned short*)(ws + 33554432);     // dead after k_conv
  c2*             G     = (c2*)(ws + 33554432);                 // aliases xT (safe)
  unsigned short* wPack = (unsigned short*)(ws + 100663296);    // 147,456 B
  float*          attn  = (float*)(ws + 100663296 + 147456);    // 16,384 B
  float*          part  = (float*)(ws + 100663296 + 147456 + 16384); // 73,728 B

  k_wpack<<<288, 256, 0, stream>>>(conv_w, wPack);
  k_xpose<<<512, 256, 0, stream>>>(x, xT);
  k_conv<<<dim3(8,8,NB), 256, 0, stream>>>(xT, wPack, bn1_g, bn1_b, bn1_m, bn1_v, feat);
  k_attn1<<<dim3(NB*NHEADS, 8), 256, 0, stream>>>(feat, part);
  k_attn2<<<NB*NHEADS, 64, 0, stream>>>(part, tau, attn);
  k_fftA<<<NB*CDN, 256, 0, stream>>>(feat, G);
  k_outf<<<dim3(NB*NHEADS, 64), 256, 0, stream>>>(feat, attn, x, out);
  k_gateB<<<NB*128, 256, 0, stream>>>(G, cg1_w, cg1_b, cgbn_g, cgbn_b, cgbn_m, cgbn_v, cg2_w, cg2_b);
  k_fftC<<<NB*CDN, 256, 0, stream>>>(G, x, out);
}

// Round 5
// 288.848 us; speedup vs baseline: 2.0390x; 1.1746x over previous
//
#include <hip/hip_runtime.h>
#include <hip/hip_bf16.h>
#include <math.h>

#define NB 8
#define CIN 128
#define CDN 64
#define NPIX 16384            // 128*128
#define NHEADS 8
#define HDIM 8

typedef __attribute__((ext_vector_type(8))) short bf16x8;
typedef __attribute__((ext_vector_type(4))) float f32x4;
typedef __attribute__((ext_vector_type(8))) unsigned short u16x8;
typedef __attribute__((ext_vector_type(4))) unsigned short u16x4;

struct alignas(8) c2 { float x, y; };

__device__ inline c2 cadd(c2 a, c2 b){ return {a.x+b.x, a.y+b.y}; }
__device__ inline c2 csub(c2 a, c2 b){ return {a.x-b.x, a.y-b.y}; }
__device__ inline c2 cmul(c2 a, c2 b){ return {a.x*b.x - a.y*b.y, a.x*b.y + a.y*b.x}; }
__device__ inline c2 shfl2(c2 v, int m){ return { __shfl_xor(v.x, m, 64), __shfl_xor(v.y, m, 64) }; }
__device__ inline float gelu_exact(float v){ return 0.5f*v*(1.f + erff(v*0.70710678118654752f)); }
__device__ inline unsigned short f2bf(float f){
  __hip_bfloat16 h = __float2bfloat16(f);
  return *reinterpret_cast<unsigned short*>(&h);
}

// ---- twiddle-hoisted 128-pt wave FFT: lane t holds positions t and t+64 ----
struct Tw { c2 t0; c2 t[6]; };
__device__ inline void tw_init(Tw& w, int t){
  float sn, cs;
  sincosf(-6.283185307179586f * (float)t * (1.f/128.f), &sn, &cs); w.t0 = {cs, sn};
  #pragma unroll
  for (int i = 0; i < 6; ++i) {
    int sp = 32 >> i;
    int j = t & (sp-1);
    sincosf(-3.141592653589793f * (float)j / (float)sp, &sn, &cs);
    w.t[i] = {cs, sn};
  }
}
// forward DIF: natural in -> slot order out
__device__ inline void fft128_fwd(c2& a, c2& b, int t, const Tw& w){
  c2 s = cadd(a,b), d = csub(a,b);
  a = s; b = cmul(d, w.t0);
  #pragma unroll
  for (int i = 0; i < 6; ++i) {
    int sp = 32 >> i;
    c2 oa = shfl2(a, sp), ob = shfl2(b, sp);
    c2 tw = w.t[i];
    if (t & sp) { a = cmul(csub(oa,a), tw); b = cmul(csub(ob,b), tw); }
    else        { a = cadd(a,oa);           b = cadd(b,ob); }
  }
}
// inverse DIT (no scaling): slot order in -> natural out
__device__ inline void fft128_inv(c2& a, c2& b, int t, const Tw& w){
  #pragma unroll
  for (int i = 5; i >= 0; --i) {
    int sp = 32 >> i;
    c2 tw = {w.t[i].x, -w.t[i].y};
    c2 oa = shfl2(a, sp), ob = shfl2(b, sp);
    if (t & sp) { a = csub(oa, cmul(a, tw)); b = csub(ob, cmul(b, tw)); }
    else        { a = cadd(a, cmul(oa, tw)); b = cadd(b, cmul(ob, tw)); }
  }
  c2 t0c = {w.t0.x, -w.t0.y};
  c2 wb = cmul(b, t0c);
  b = csub(a, wb);
  a = cadd(a, wb);
}

__device__ inline void gload_lds16(const void* g, void* l){
  __builtin_amdgcn_global_load_lds(
      (const __attribute__((address_space(1))) unsigned int*)g,
      (__attribute__((address_space(3))) unsigned int*)l, 16, 0, 0);
}

// conv_w fp32 [64co][128ci][3][3] -> wPack bf16 [cc=2][tap=9][co=64][ci=64]
__global__ __launch_bounds__(256) void k_wpack(const float* __restrict__ w, unsigned short* __restrict__ wP){
  int idx = blockIdx.x*256 + threadIdx.x;
  if (idx >= 2*9*64*64) return;
  int cc  = idx / 36864;
  int r   = idx - cc*36864;
  int tap = r / 4096;
  int r2  = r - tap*4096;
  int co  = r2 >> 6;
  int cil = r2 & 63;
  int ci  = cc*64 + cil;
  wP[idx] = f2bf(w[(co*CIN + ci)*9 + tap]);
}

// x fp32 [b][128ci][16384p] -> xT bf16 [b][2cc][16384p][64ci]
__global__ __launch_bounds__(256) void k_xpose(const float* __restrict__ x, unsigned short* __restrict__ xT){
  int b = blockIdx.x >> 6;
  int px = (blockIdx.x & 63)*256 + threadIdx.x;
  const float* xb = x + (size_t)b*CIN*NPIX + px;
  #pragma unroll 2
  for (int ci0 = 0; ci0 < 128; ci0 += 8) {
    u16x8 v;
    #pragma unroll
    for (int j = 0; j < 8; ++j) v[j] = f2bf(xb[(size_t)(ci0+j)*NPIX]);
    int cc = ci0 >> 6;
    *(u16x8*)(xT + (((size_t)(b*2+cc)*NPIX + px)*64 + (ci0 & 63))) = v;
  }
}

// Dilated 3x3 conv (dil=3,pad=3) + BN + exact GELU via bf16 MFMA implicit GEMM.
__global__ __launch_bounds__(256) void k_conv(const unsigned short* __restrict__ xT,
    const unsigned short* __restrict__ wP,
    const float* __restrict__ bg, const float* __restrict__ bbeta,
    const float* __restrict__ bm, const float* __restrict__ bv,
    float* __restrict__ feat){
  __shared__ __align__(16) unsigned short sX[4096*8];   // 512 px x 64 ci bf16 (484 used)
  const int tid = threadIdx.x;
  const int bb = blockIdx.z;
  const int x0 = blockIdx.x * 16, y0 = blockIdx.y * 16;
  const int wv  = tid >> 6;
  const int l   = tid & 63;
  const int l15 = l & 15;
  const int g   = l >> 4;

  const bool interior = (x0 >= 16) && (x0 <= 96) && (y0 >= 16) && (y0 <= 96);

  f32x4 acc[4][4];
  #pragma unroll
  for (int m=0;m<4;++m)
    #pragma unroll
    for (int n=0;n<4;++n) acc[m][n] = {0.f,0.f,0.f,0.f};

  for (int cc = 0; cc < 2; ++cc) {
    __syncthreads();
    const unsigned short* xcc = xT + ((size_t)(bb*2 + cc))*NPIX*64;
    if (interior) {
      #pragma unroll
      for (int k = 0; k < 16; ++k) {
        int blk = k*4 + wv;
        int idx = blk*64 + l;
        int p = idx >> 3, gr = idx & 7;
        int pc = p < 484 ? p : 483;
        int py = pc / 22, px = pc - py*22;
        int gpix = (y0-3+py)*128 + (x0-3+px);
        int sg = gr ^ (p & 7);
        const unsigned short* srcp = xcc + (size_t)gpix*64 + sg*8;
        gload_lds16(srcp, (char*)sX + blk*1024);
      }
    } else {
      #pragma unroll
      for (int k = 0; k < 16; ++k) {
        int idx = k*256 + tid;
        int p = idx >> 3, gr = idx & 7;
        u16x8 v = {0,0,0,0,0,0,0,0};
        if (p < 484) {
          int py = p / 22, px = p - py*22;
          int gy = y0-3+py, gx = x0-3+px;
          if ((unsigned)gy < 128u && (unsigned)gx < 128u) {
            int sg = gr ^ (p & 7);
            v = *(const u16x8*)(xcc + (size_t)(gy*128+gx)*64 + sg*8);
          }
        }
        *(u16x8*)((char*)sX + idx*16) = v;
      }
    }
    __syncthreads();

    const unsigned short* wcc = wP + cc*36864;
    for (int tap = 0; tap < 9; ++tap) {
      int dy = (tap/3)*3, dx = (tap - (tap/3)*3)*3;
      const unsigned short* wt = wcc + tap*4096;
      #pragma unroll
      for (int kc = 0; kc < 2; ++kc) {
        bf16x8 a[4], b[4];
        int ko = kc*32 + g*8;
        #pragma unroll
        for (int m = 0; m < 4; ++m)
          a[m] = *reinterpret_cast<const bf16x8*>(wt + (m*16 + l15)*64 + ko);
        #pragma unroll
        for (int n = 0; n < 4; ++n) {
          int p = (wv*4 + n + dy)*22 + l15 + dx;
          b[n] = *reinterpret_cast<const bf16x8*>(&sX[p*64 + (ko ^ ((p & 7) << 3))]);
        }
        #pragma unroll
        for (int m = 0; m < 4; ++m)
          #pragma unroll
          for (int n = 0; n < 4; ++n)
            acc[m][n] = __builtin_amdgcn_mfma_f32_16x16x32_bf16(a[m], b[n], acc[m][n], 0, 0, 0);
      }
    }
  }

  #pragma unroll
  for (int m = 0; m < 4; ++m) {
    #pragma unroll
    for (int r = 0; r < 4; ++r) {
      int co = m*16 + g*4 + r;
      float sc = bg[co] * rsqrtf(bv[co] + 1e-5f);
      float sh = bbeta[co] - bm[co]*sc;
      #pragma unroll
      for (int n = 0; n < 4; ++n) {
        int py = wv*4 + n;
        float v = acc[m][n][r]*sc + sh;
        feat[((size_t)(bb*CDN + co)*128 + (y0+py))*128 + x0 + l15] = gelu_exact(v);
      }
    }
  }
}

// stage 1: partial 8x8 Gram over 2048-pixel chunks -> part[bh*8+ck][36]
__global__ __launch_bounds__(256) void k_attn1(const float* __restrict__ feat, float* __restrict__ part){
  int bh = blockIdx.x, ck = blockIdx.y;
  int b = bh >> 3, h = bh & 7;
  const float* f = feat + (size_t)(b*CDN + h*HDIM)*NPIX;
  float acc[36];
  #pragma unroll
  for (int i=0;i<36;++i) acc[i]=0.f;
  for (int p = ck*2048 + threadIdx.x; p < (ck+1)*2048; p += 256) {
    float v[8];
    #pragma unroll
    for (int d=0; d<8; ++d) v[d] = f[d*NPIX + p];
    int i = 0;
    #pragma unroll
    for (int d=0; d<8; ++d)
      #pragma unroll
      for (int e=0; e<=d; ++e) acc[i++] += v[d]*v[e];
  }
  #pragma unroll
  for (int i=0;i<36;++i)
    #pragma unroll
    for (int off=32; off; off>>=1) acc[i] += __shfl_xor(acc[i], off, 64);
  __shared__ float red[4][36];
  int wave = threadIdx.x >> 6, lane = threadIdx.x & 63;
  if (lane == 0) {
    #pragma unroll
    for (int i=0;i<36;++i) red[wave][i] = acc[i];
  }
  __syncthreads();
  if (threadIdx.x < 36)
    part[(bh*8+ck)*36 + threadIdx.x] =
      red[0][threadIdx.x]+red[1][threadIdx.x]+red[2][threadIdx.x]+red[3][threadIdx.x];
}

// stage 2: reduce partials, build softmax'd attention matrix
__global__ __launch_bounds__(64) void k_attn2(const float* __restrict__ part, const float* __restrict__ tau,
                                              float* __restrict__ attn){
  int bh = blockIdx.x; int h = bh & 7;
  __shared__ float Gm[36];
  int i = threadIdx.x;
  if (i < 36) {
    float s = 0.f;
    #pragma unroll
    for (int k = 0; k < 8; ++k) s += part[(bh*8+k)*36 + i];
    Gm[i] = s;
  }
  __syncthreads();
  if (i == 0) {
    float G[8][8];
    int c=0;
    for (int d=0;d<8;++d) for(int e=0;e<=d;++e){
      float s = Gm[c]; G[d][e]=s; G[e][d]=s; ++c;
    }
    float nrm[8];
    for (int d=0;d<8;++d) nrm[d] = sqrtf(16384.f*G[d][d] + 1e-6f);
    float tv = tau[h];
    for (int d=0;d<8;++d) {
      float row[8]; float mx = -1e30f;
      for (int e=0;e<8;++e){ row[e] = tv*16384.f*G[d][e]/(nrm[d]*nrm[e]); mx = fmaxf(mx,row[e]); }
      float s=0.f;
      for (int e=0;e<8;++e){ row[e] = expf(row[e]-mx); s += row[e]; }
      for (int e=0;e<8;++e) attn[bh*64 + d*8 + e] = row[e]/s;
    }
  }
}

// out_f = sqrt((attn @ feat)^2 + (mean_e feat)^2) + x   (channels 0..63)
__global__ __launch_bounds__(256) void k_outf(const float* __restrict__ feat, const float* __restrict__ attn,
                                              const float* __restrict__ x, float* __restrict__ out){
  int bh = blockIdx.x; int b = bh >> 3, h = bh & 7;
  int p = blockIdx.y*256 + threadIdx.x;
  __shared__ float A[64];
  if (threadIdx.x < 64) A[threadIdx.x] = attn[bh*64 + threadIdx.x];
  __syncthreads();
  const float* f = feat + (size_t)(b*CDN + h*HDIM)*NPIX;
  float v[8];
  #pragma unroll
  for (int e=0;e<8;++e) v[e] = f[e*NPIX + p];
  float im = 0.f;
  #pragma unroll
  for (int e=0;e<8;++e) im += v[e];
  im *= 0.125f;
  #pragma unroll
  for (int d=0;d<8;++d){
    float re = 0.f;
    #pragma unroll
    for (int e=0;e<8;++e) re += A[d*8+e]*v[e];
    size_t o = ((size_t)(b*CIN + h*HDIM + d))*NPIX + p;
    out[o] = sqrtf(re*re + im*im) + x[o];
  }
}

#define TASTR 129
// row FFT over x + transposed write: feat -> G[b][c][sx][y], 32-row chunks (33KB LDS)
__global__ __launch_bounds__(256) void k_fftA(const float* __restrict__ feat, c2* __restrict__ G){
  __shared__ c2 T[32*TASTR];
  int ib = blockIdx.x;
  int tid = threadIdx.x, wv = tid >> 6, t = tid & 63;
  Tw w; tw_init(w, t);
  const float* src = feat + (size_t)ib*NPIX;
  c2* dst = G + (size_t)ib*NPIX;
  int yl = t & 31, sh = t >> 5;
  for (int k = 0; k < 4; ++k) {
    if (k) __syncthreads();
    #pragma unroll 2
    for (int i = 0; i < 8; ++i) {
      int rl = wv*8 + i;
      int r = k*32 + rl;
      c2 a = {src[r*128 + t], 0.f};
      c2 b = {src[r*128 + t + 64], 0.f};
      fft128_fwd(a, b, t, w);
      T[rl*TASTR + t] = a;
      T[rl*TASTR + t + 64] = b;
    }
    __syncthreads();
    #pragma unroll 4
    for (int j = 0; j < 16; ++j) {
      int s = wv*32 + j*2 + sh;
      c2 v = T[yl*TASTR + s];
      dst[(size_t)s*128 + k*32 + yl] = v;
    }
  }
}

// col FFT + gate + inverse col FFT, fully in registers (ALL array indices compile-time).
// One block per (b, sx). Wave wv holds channels wv*16..wv*16+15; lane t holds y=t,t+64.
__global__ __launch_bounds__(256) void k_gateB(c2* __restrict__ G,
    const float* __restrict__ w1, const float* __restrict__ b1,
    const float* __restrict__ gg, const float* __restrict__ gbeta,
    const float* __restrict__ gm, const float* __restrict__ gv,
    const float* __restrict__ w2, const float* __restrict__ b2){
  __shared__ float P[128*17];   // 8704 B: [sy][wv*4+m]
  int b = blockIdx.x >> 7, sx = blockIdx.x & 127;
  int tid = threadIdx.x, wv = tid >> 6, t = tid & 63;
  Tw w; tw_init(w, t);
  c2* base = G + (size_t)b*CDN*NPIX + (size_t)sx*128;
  c2 d0[16], d1[16];
  #pragma unroll
  for (int i = 0; i < 16; ++i) {
    const c2* g = base + (size_t)(wv*16 + i)*NPIX;
    d0[i] = g[t]; d1[i] = g[t+64];
  }
  #pragma unroll
  for (int i = 0; i < 16; ++i) fft128_fwd(d0[i], d1[i], t, w);
  // per-wave partial mid sums at sy=t and sy=t+64
  float pm0[4] = {0,0,0,0}, pm1[4] = {0,0,0,0};
  #pragma unroll
  for (int i = 0; i < 16; ++i) {
    int ch = wv*16 + i;
    #pragma unroll
    for (int m = 0; m < 4; ++m) {
      float wc = w1[m*64+ch];
      pm0[m] += wc * d0[i].x;
      pm1[m] += wc * d1[i].x;
    }
  }
  #pragma unroll
  for (int m = 0; m < 4; ++m) {
    P[t*17 + wv*4 + m] = pm0[m];
    P[(t+64)*17 + wv*4 + m] = pm1[m];
  }
  __syncthreads();
  float mid0[4], mid1[4];
  #pragma unroll
  for (int m = 0; m < 4; ++m) {
    float s0 = b1[m], s1 = b1[m];
    #pragma unroll
    for (int k = 0; k < 4; ++k) { s0 += P[t*17 + k*4 + m]; s1 += P[(t+64)*17 + k*4 + m]; }
    float sc = gg[m]*rsqrtf(gv[m]+1e-5f);
    float sh = gbeta[m] - gm[m]*sc;
    mid0[m] = gelu_exact(s0*sc + sh);
    mid1[m] = gelu_exact(s1*sc + sh);
  }
  #pragma unroll
  for (int i = 0; i < 16; ++i) {
    int ch = wv*16 + i;
    float g0 = b2[ch], g1 = g0;
    #pragma unroll
    for (int m = 0; m < 4; ++m) { float wc = w2[ch*4+m]; g0 += wc*mid0[m]; g1 += wc*mid1[m]; }
    g0 = 1.f/(1.f+expf(-g0)); g1 = 1.f/(1.f+expf(-g1));
    d0[i].x *= g0; d0[i].y *= g0;
    d1[i].x *= g1; d1[i].y *= g1;
  }
  #pragma unroll
  for (int i = 0; i < 16; ++i) fft128_inv(d0[i], d1[i], t, w);
  #pragma unroll
  for (int i = 0; i < 16; ++i) {
    c2* g = base + (size_t)(wv*16 + i)*NPIX;
    g[t] = d0[i]; g[t+64] = d1[i];
  }
}

// inverse row FFT over sx + abs + residual -> out channels 64..127, 32-y chunks
__global__ __launch_bounds__(256) void k_fftC(const c2* __restrict__ G, const float* __restrict__ x,
                                              float* __restrict__ out){
  __shared__ c2 T[32*TASTR];
  int ib = blockIdx.x;          // b*64+c
  int b = ib >> 6, c = ib & 63;
  int tid = threadIdx.x, wv = tid >> 6, t = tid & 63;
  Tw w; tw_init(w, t);
  const c2* src = G + (size_t)ib*NPIX;
  const float* xr = x + ((size_t)(b*CIN + 64 + c))*NPIX;
  float* orow = out + ((size_t)(b*CIN + 64 + c))*NPIX;
  const float sc = 1.f/16384.f;
  int yl = t & 31, sh = t >> 5;
  for (int k = 0; k < 4; ++k) {
    if (k) __syncthreads();
    #pragma unroll 4
    for (int j = 0; j < 16; ++j) {
      int s = wv*32 + j*2 + sh;
      c2 v = src[(size_t)s*128 + k*32 + yl];
      T[yl*TASTR + s] = v;
    }
    __syncthreads();
    #pragma unroll 2
    for (int i = 0; i < 8; ++i) {
      int yl2 = wv*8 + i;
      int y = k*32 + yl2;
      c2 a = T[yl2*TASTR + t];
      c2 bb = T[yl2*TASTR + t + 64];
      fft128_inv(a, bb, t, w);
      orow[y*128 + t]      = sqrtf(a.x*a.x + a.y*a.y)*sc + xr[y*128 + t];
      orow[y*128 + t + 64] = sqrtf(bb.x*bb.x + bb.y*bb.y)*sc + xr[y*128 + t + 64];
    }
  }
}

extern "C" void kernel_launch(void* const* d_in, const int* in_sizes, int n_in,
                              void* d_out, int out_size, void* d_ws, size_t ws_size,
                              hipStream_t stream){
  const float* x      = (const float*)d_in[0];
  const float* conv_w = (const float*)d_in[1];
  const float* bn1_g  = (const float*)d_in[2];
  const float* bn1_b  = (const float*)d_in[3];
  const float* bn1_m  = (const float*)d_in[4];
  const float* bn1_v  = (const float*)d_in[5];
  const float* cg1_w  = (const float*)d_in[6];
  const float* cg1_b  = (const float*)d_in[7];
  const float* cgbn_g = (const float*)d_in[8];
  const float* cgbn_b = (const float*)d_in[9];
  const float* cgbn_m = (const float*)d_in[10];
  const float* cgbn_v = (const float*)d_in[11];
  const float* cg2_w  = (const float*)d_in[12];
  const float* cg2_b  = (const float*)d_in[13];
  const float* tau    = (const float*)d_in[14];
  float* out = (float*)d_out;

  char* ws = (char*)d_ws;
  float*          feat  = (float*)ws;                           // [0, 33.5M)
  unsigned short* xT    = (unsigned short*)(ws + 33554432);     // dead after k_conv
  c2*             G     = (c2*)(ws + 33554432);                 // aliases xT (safe)
  unsigned short* wPack = (unsigned short*)(ws + 100663296);    // 147,456 B
  float*          attn  = (float*)(ws + 100663296 + 147456);    // 16,384 B
  float*          part  = (float*)(ws + 100663296 + 147456 + 16384); // 73,728 B

  k_wpack<<<288, 256, 0, stream>>>(conv_w, wPack);
  k_xpose<<<512, 256, 0, stream>>>(x, xT);
  k_conv<<<dim3(8,8,NB), 256, 0, stream>>>(xT, wPack, bn1_g, bn1_b, bn1_m, bn1_v, feat);
  k_attn1<<<dim3(NB*NHEADS, 8), 256, 0, stream>>>(feat, part);
  k_attn2<<<NB*NHEADS, 64, 0, stream>>>(part, tau, attn);
  k_fftA<<<NB*CDN, 256, 0, stream>>>(feat, G);
  k_outf<<<dim3(NB*NHEADS, 64), 256, 0, stream>>>(feat, attn, x, out);
  k_gateB<<<NB*128, 256, 0, stream>>>(G, cg1_w, cg1_b, cgbn_g, cgbn_b, cgbn_m, cgbn_v, cg2_w, cg2_b);
  k_fftC<<<NB*CDN, 256, 0, stream>>>(G, x, out);
}